// Round 7
// baseline (565.686 us; speedup 1.0000x reference)
//
#include <hip/hip_runtime.h>
#include <hip/hip_bf16.h>

#define NTHREADS 256

typedef unsigned int uint32;
typedef unsigned long long u64;
typedef uint32 uv4 __attribute__((ext_vector_type(4)));
typedef float  fv4 __attribute__((ext_vector_type(4)));

// ---------------- bf16 helpers ----------------

__device__ __forceinline__ float blo(uint32 u) { return __uint_as_float(u << 16); }
__device__ __forceinline__ float bhi(uint32 u) { return __uint_as_float(u & 0xffff0000u); }

__device__ __forceinline__ unsigned short bf16bits(float f) {
    __hip_bfloat16 h = __float2bfloat16(f);
    return *reinterpret_cast<unsigned short*>(&h);
}
__device__ __forceinline__ uint32 pk2(float a, float b) {
    return (uint32)bf16bits(a) | ((uint32)bf16bits(b) << 16);
}

// Padded atomic layout: one node per 64B line. atom[i*16] = count, atom[i*16+8] = deg(f32).
#define APAD 16

__global__ void atom_init_k(int* atom, int n) {
    int i = blockIdx.x * blockDim.x + threadIdx.x;
    if (i < n) { atom[(size_t)i * APAD] = 0; atom[(size_t)i * APAD + 8] = 0; }  // 0 == 0.0f
}

__global__ void edge_pass1_k(const int* __restrict__ row, const int* __restrict__ col,
                             const float* __restrict__ w, int* atom,
                             int* __restrict__ pos, int e) {
    int i = blockIdx.x * blockDim.x + threadIdx.x;
    if (i < e) {
        int r = __builtin_nontemporal_load(&row[i]);
        int c = __builtin_nontemporal_load(&col[i]);
        float wv = __builtin_nontemporal_load(&w[i]);
        unsafeAtomicAdd((float*)&atom[(size_t)r * APAD + 8], wv);
        int p = atomicAdd(&atom[(size_t)c * APAD], 1);
        __builtin_nontemporal_store(p, &pos[i]);
    }
}

__global__ void dinv_k(const int* __restrict__ atom, float* dinv, int n) {
    int i = blockIdx.x * blockDim.x + threadIdx.x;
    if (i < n) {
        float deg = ((const float*)atom)[(size_t)i * APAD + 8] + 1.0f;  // +1 self-loop
        dinv[i] = rsqrtf(fmaxf(deg, 1e-12f));
    }
}

// ---------------- CSR offsets (scan over padded counts) ----------------

__global__ void scan1_k(const int* __restrict__ atom, int* offsets, int* blockSums, int n) {
    __shared__ int s[256];
    int tid = threadIdx.x;
    int idx = blockIdx.x * 256 + tid;
    int v = (idx < n) ? atom[(size_t)idx * APAD] : 0;
    s[tid] = v;
    __syncthreads();
    for (int off = 1; off < 256; off <<= 1) {
        int t = (tid >= off) ? s[tid - off] : 0;
        __syncthreads();
        s[tid] += t;
        __syncthreads();
    }
    if (idx < n) offsets[idx] = s[tid] - v;
    if (tid == 255) blockSums[blockIdx.x] = s[255];
}

__global__ void scan2_k(int* blockSums, int nb) {
    __shared__ int s[1024];
    int tid = threadIdx.x;
    int v = (tid < nb) ? blockSums[tid] : 0;
    s[tid] = v;
    __syncthreads();
    for (int off = 1; off < 1024; off <<= 1) {
        int t = (tid >= off) ? s[tid - off] : 0;
        __syncthreads();
        s[tid] += t;
        __syncthreads();
    }
    if (tid < nb) blockSums[tid] = s[tid] - v;
}

__global__ void scan3_k(int* offsets, const int* __restrict__ blockSums, int n, int total) {
    int idx = blockIdx.x * blockDim.x + threadIdx.x;
    if (idx < n) offsets[idx] += blockSums[idx >> 8];
    if (idx == n) offsets[n] = total;
}

// ---------------- atomic-free scatter: csr = (src, RAW w) ----------------

__global__ void scatter_k(const int* __restrict__ row, const int* __restrict__ col,
                          const float* __restrict__ w,
                          const int* __restrict__ offsets, const int* __restrict__ pos,
                          u64* __restrict__ csr, int e) {
    int i = blockIdx.x * blockDim.x + threadIdx.x;
    if (i >= e) return;
    int r = __builtin_nontemporal_load(&row[i]);
    int c = __builtin_nontemporal_load(&col[i]);
    float wv = __builtin_nontemporal_load(&w[i]);
    int pp = __builtin_nontemporal_load(&pos[i]);
    int p = offsets[c] + pp;
    u64 rec = (u64)(uint32)r | ((u64)(uint32)__float_as_uint(wv) << 32);
    __builtin_nontemporal_store(rec, &csr[p]);
}

// ---------------- u-seed: ux = bf16(dinv * x), 2 floats / thread ----------------

__global__ void uxseed_k(const float* __restrict__ x, const float* __restrict__ dinv,
                         uint32* __restrict__ ux, int pairs) {
    int i = blockIdx.x * blockDim.x + threadIdx.x;
    if (i < pairs) {
        float di = dinv[i >> 5];          // 32 pairs per node
        float2 v = ((const float2*)x)[i];
        __builtin_nontemporal_store(pk2(di * v.x, di * v.y), &ux[i]);
    }
}

// ---------------- Horner in u-space: 4 nodes per wave, csr-prefetch pipeline ----------------
// u = D^-1/2 z.  u_j = ux + dd * (W u_{j-1}),  (W u)[c] = u[c] + sum_e w_e u[src_e]
// MODE 0: u_out = bf16( ux + dd * (W u_in) )
// MODE 1: ybf   = bf16( 0.09*dinv*(W u_in) + 0.1*x )

template <int MODE>
__global__ __launch_bounds__(256) void horner4n_k(
    const unsigned short* __restrict__ u_in,
    unsigned short* __restrict__ u_out,
    unsigned short* __restrict__ ybf,
    const unsigned short* __restrict__ ux_bf,
    const float* __restrict__ x,
    const float* __restrict__ dinv,
    const int* __restrict__ offsets,
    const u64* __restrict__ csr,
    int n)
{
    int wv = __builtin_amdgcn_readfirstlane(threadIdx.x >> 6);
    int lane = threadIdx.x & 63;
    int g = lane >> 3;   // group
    int s = lane & 7;    // 16B slice of a 128B bf16 row
    int nbase = blockIdx.x * 16 + wv * 4;

    int bb[4], ee[4];
#pragma unroll
    for (int m = 0; m < 4; ++m) {
        int node = nbase + m;
        if (node < n) { bb[m] = offsets[node]; ee[m] = offsets[node + 1]; }
        else          { bb[m] = 0; ee[m] = 0; }
    }
    int maxd = max(max(ee[0] - bb[0], ee[1] - bb[1]), max(ee[2] - bb[2], ee[3] - bb[3]));

    float acc[4][8];
#pragma unroll
    for (int m = 0; m < 4; ++m)
#pragma unroll
        for (int i = 0; i < 8; ++i) acc[m][i] = 0.f;

    // prologue: load first csr batch (NT — stream, keep L2 for gathers)
    u64 sw[4];
#pragma unroll
    for (int m = 0; m < 4; ++m) {
        int j = bb[m] + g;
        sw[m] = (j < ee[m]) ? __builtin_nontemporal_load(&csr[j]) : 0ull;
    }

    for (int off = 0; off < maxd; off += 8) {
        // issue gathers for current batch (cached — reuse is the point)
        uint4 q[4];
#pragma unroll
        for (int m = 0; m < 4; ++m)
            q[m] = ((const uint4*)(u_in + (size_t)(uint32)(sw[m] & 0xffffffffu) * 64))[s];
        // prefetch next csr batch (overlaps with gathers)
        u64 swn[4];
#pragma unroll
        for (int m = 0; m < 4; ++m) {
            int j = bb[m] + off + 8 + g;
            swn[m] = (j < ee[m]) ? __builtin_nontemporal_load(&csr[j]) : 0ull;
        }
        // consume gathers
#pragma unroll
        for (int m = 0; m < 4; ++m) {
            float w = __uint_as_float((uint32)(sw[m] >> 32));
            acc[m][0] = fmaf(w, blo(q[m].x), acc[m][0]);
            acc[m][1] = fmaf(w, bhi(q[m].x), acc[m][1]);
            acc[m][2] = fmaf(w, blo(q[m].y), acc[m][2]);
            acc[m][3] = fmaf(w, bhi(q[m].y), acc[m][3]);
            acc[m][4] = fmaf(w, blo(q[m].z), acc[m][4]);
            acc[m][5] = fmaf(w, bhi(q[m].z), acc[m][5]);
            acc[m][6] = fmaf(w, blo(q[m].w), acc[m][6]);
            acc[m][7] = fmaf(w, bhi(q[m].w), acc[m][7]);
        }
#pragma unroll
        for (int m = 0; m < 4; ++m) sw[m] = swn[m];
    }

    // butterfly across the 8 groups (lane bits 3,4,5)
#pragma unroll
    for (int mask = 8; mask <= 32; mask <<= 1)
#pragma unroll
        for (int m = 0; m < 4; ++m)
#pragma unroll
            for (int i = 0; i < 8; ++i)
                acc[m][i] += __shfl_xor(acc[m][i], mask);

    // select node-g's sums with a static-index cndmask tree (no scratch)
    float t[8];
#pragma unroll
    for (int i = 0; i < 8; ++i) {
        float a01 = (g == 0) ? acc[0][i] : acc[1][i];
        float a23 = (g == 2) ? acc[2][i] : acc[3][i];
        t[i] = (g < 2) ? a01 : a23;
    }

    if (g < 4) {
        int node = nbase + g;
        if (node < n) {
            float di = dinv[node];
            uint4 zq = ((const uint4*)(u_in + (size_t)node * 64))[s];  // self u-row (shared -> cached)
            t[0] += blo(zq.x); t[1] += bhi(zq.x);
            t[2] += blo(zq.y); t[3] += bhi(zq.y);
            t[4] += blo(zq.z); t[5] += bhi(zq.z);
            t[6] += blo(zq.w); t[7] += bhi(zq.w);
            if (MODE == 0) {
                float dd = di * di;
                uv4 xq = __builtin_nontemporal_load(
                    (const uv4*)(ux_bf + (size_t)node * 64) + s);     // owner-only -> NT
                uv4 o;
                o.x = pk2(fmaf(dd, t[0], blo(xq.x)), fmaf(dd, t[1], bhi(xq.x)));
                o.y = pk2(fmaf(dd, t[2], blo(xq.y)), fmaf(dd, t[3], bhi(xq.y)));
                o.z = pk2(fmaf(dd, t[4], blo(xq.z)), fmaf(dd, t[5], bhi(xq.z)));
                o.w = pk2(fmaf(dd, t[6], blo(xq.w)), fmaf(dd, t[7], bhi(xq.w)));
                __builtin_nontemporal_store(o, (uv4*)(u_out + (size_t)node * 64) + s);
            } else {
                float c = 0.09f * di;
                fv4 xa = __builtin_nontemporal_load((const fv4*)(x + (size_t)node * 64) + s * 2);
                fv4 xb = __builtin_nontemporal_load((const fv4*)(x + (size_t)node * 64) + s * 2 + 1);
                uv4 o;
                o.x = pk2(fmaf(c, t[0], 0.1f * xa.x), fmaf(c, t[1], 0.1f * xa.y));
                o.y = pk2(fmaf(c, t[2], 0.1f * xa.z), fmaf(c, t[3], 0.1f * xa.w));
                o.z = pk2(fmaf(c, t[4], 0.1f * xb.x), fmaf(c, t[5], 0.1f * xb.y));
                o.w = pk2(fmaf(c, t[6], 0.1f * xb.z), fmaf(c, t[7], 0.1f * xb.w));
                __builtin_nontemporal_store(o, (uv4*)(ybf + (size_t)node * 64) + s);
            }
        }
    }
}

// ---------------- MLP epilogue: y @ W0 relu @ W1 (y in bf16) ----------------

__global__ __launch_bounds__(256) void mlp_k(const unsigned short* __restrict__ ybf,
                                             const float* __restrict__ W0,
                                             const float* __restrict__ b0,
                                             const float* __restrict__ W1,
                                             const float* __restrict__ b1,
                                             float* __restrict__ out, int n) {
    __shared__ float W0s[64 * 64];
    __shared__ float W1s[64 * 32];
    __shared__ float b0s[64];
    __shared__ float b1s[32];
    __shared__ float z[32][64];
    __shared__ float hid[32][64];
    int tid = threadIdx.x;
    for (int i = tid; i < 64 * 64; i += 256) W0s[i] = W0[i];
    for (int i = tid; i < 64 * 32; i += 256) W1s[i] = W1[i];
    if (tid < 64) b0s[tid] = b0[tid];
    else if (tid < 96) b1s[tid - 64] = b1[tid - 64];

    int base = blockIdx.x * 32;
    const uint32* y32 = (const uint32*)ybf;
    for (int r = 0; r < 4; ++r) {
        int idx = r * 256 + tid;       // 1024 uints = 32 nodes x 32 uints
        int nn = idx >> 5, f2 = idx & 31;
        int node = base + nn;
        uint32 v = (node < n) ? y32[(size_t)node * 32 + f2] : 0u;
        z[nn][f2 * 2]     = blo(v);
        z[nn][f2 * 2 + 1] = bhi(v);
    }
    __syncthreads();
    for (int r = 0; r < 8; ++r) {
        int idx = r * 256 + tid;
        int nn = idx >> 6, j = idx & 63;
        float s = b0s[j];
#pragma unroll
        for (int i = 0; i < 64; ++i) s += z[nn][i] * W0s[i * 64 + j];
        hid[nn][j] = fmaxf(s, 0.f);
    }
    __syncthreads();
    for (int r = 0; r < 4; ++r) {
        int idx = r * 256 + tid;
        int nn = idx >> 5, o = idx & 31;
        int node = base + nn;
        if (node >= n) continue;
        float s = b1s[o];
#pragma unroll
        for (int i = 0; i < 64; ++i) s += hid[nn][i] * W1s[i * 32 + o];
        out[(size_t)node * 32 + o] = s;
    }
}

// ---------------- launch ----------------

extern "C" void kernel_launch(void* const* d_in, const int* in_sizes, int n_in,
                              void* d_out, int out_size, void* d_ws, size_t ws_size,
                              hipStream_t stream) {
    const float* x   = (const float*)d_in[0];
    const int*   ei  = (const int*)d_in[1];
    const float* ew  = (const float*)d_in[2];
    const float* W0  = (const float*)d_in[3];
    const float* b0  = (const float*)d_in[4];
    const float* W1  = (const float*)d_in[5];
    const float* b1  = (const float*)d_in[6];
    float* out = (float*)d_out;

    const int N = in_sizes[0] / 64;   // 100000
    const int E = in_sizes[2];        // 1200000
    const int* row = ei;
    const int* col = ei + E;

    char* p = (char*)d_ws;
    auto alloc = [&](size_t bytes) -> void* {
        void* r = (void*)p;
        p += (bytes + 255) & ~(size_t)255;
        return r;
    };
    int*   atom      = (int*)alloc((size_t)N * APAD * 4);   // padded count+deg, 64B/node
    float* dinv      = (float*)alloc((size_t)N * 4);
    int*   offsets   = (int*)alloc((size_t)(N + 1) * 4);
    int    nb        = (N + 255) / 256;
    int*   blockSums = (int*)alloc((size_t)nb * 4);
    int*   pos       = (int*)alloc((size_t)E * 4);
    u64*   csr       = (u64*)alloc((size_t)E * 8);
    unsigned short* uxbf = (unsigned short*)alloc((size_t)N * 64 * 2);  // dinv*x bf16 == u0
    unsigned short* uA   = (unsigned short*)alloc((size_t)N * 64 * 2);
    unsigned short* uB   = (unsigned short*)alloc((size_t)N * 64 * 2);
    unsigned short* ybf  = (unsigned short*)alloc((size_t)N * 64 * 2);

    int gN = (N + NTHREADS - 1) / NTHREADS;
    int gE = (E + NTHREADS - 1) / NTHREADS;

    atom_init_k<<<gN, NTHREADS, 0, stream>>>(atom, N);
    edge_pass1_k<<<gE, NTHREADS, 0, stream>>>(row, col, ew, atom, pos, E);
    dinv_k<<<gN, NTHREADS, 0, stream>>>(atom, dinv, N);

    scan1_k<<<nb, 256, 0, stream>>>(atom, offsets, blockSums, N);
    scan2_k<<<1, 1024, 0, stream>>>(blockSums, nb);
    scan3_k<<<(N + 1 + NTHREADS - 1) / NTHREADS, NTHREADS, 0, stream>>>(offsets, blockSums, N, E);
    scatter_k<<<gE, NTHREADS, 0, stream>>>(row, col, ew, offsets, pos, csr, E);

    int pairs = N * 32;
    uxseed_k<<<(pairs + NTHREADS - 1) / NTHREADS, NTHREADS, 0, stream>>>(x, dinv,
                                                                         (uint32*)uxbf, pairs);

    // 9 Horner steps in u-space; first input is uxbf (= u0)
    int gP = (N + 15) / 16;
    const unsigned short* ui = uxbf;
    for (int k = 1; k <= 9; ++k) {
        unsigned short* uo = (ui == uA) ? uB : uA;
        horner4n_k<0><<<gP, 256, 0, stream>>>(ui, uo, nullptr, uxbf, x, dinv, offsets, csr, N);
        ui = uo;
    }
    // final: ybf = bf16(0.09*dinv*(W u_9) + 0.1*x)
    horner4n_k<1><<<gP, 256, 0, stream>>>(ui, nullptr, ybf, uxbf, x, dinv, offsets, csr, N);

    mlp_k<<<(N + 31) / 32, 256, 0, stream>>>(ybf, W0, b0, W1, b1, out, N);
}

// Round 8
// 553.498 us; speedup vs baseline: 1.0220x; 1.0220x over previous
//
#include <hip/hip_runtime.h>
#include <hip/hip_bf16.h>

#define NTHREADS 256
#define NREP 8
#define NBUCKET 64

typedef unsigned int uint32;
typedef unsigned long long u64;

// ---------------- bf16 helpers ----------------

__device__ __forceinline__ float blo(uint32 u) { return __uint_as_float(u << 16); }
__device__ __forceinline__ float bhi(uint32 u) { return __uint_as_float(u & 0xffff0000u); }

__device__ __forceinline__ unsigned short bf16bits(float f) {
    __hip_bfloat16 h = __float2bfloat16(f);
    return *reinterpret_cast<unsigned short*>(&h);
}
__device__ __forceinline__ uint32 pk2(float a, float b) {
    return (uint32)bf16bits(a) | ((uint32)bf16bits(b) << 16);
}

// ---------------- replica init ----------------

__global__ void repinit_k(int* counts_r, float* deg_r, int* bucketCount, int n8) {
    int i = blockIdx.x * blockDim.x + threadIdx.x;
    if (i < n8) { counts_r[i] = 0; deg_r[i] = 0.f; }
    if (i < NBUCKET) bucketCount[i] = 0;
}

// ---------------- edge pass: XCD-cohort replicated atomics ----------------

__global__ void edge_pass1_k(const int* __restrict__ row, const int* __restrict__ col,
                             const float* __restrict__ w, int* counts_r, float* deg_r,
                             int* __restrict__ pos, int e, int n) {
    int i = blockIdx.x * blockDim.x + threadIdx.x;
    int rep = blockIdx.x & (NREP - 1);
    if (i < e) {
        unsafeAtomicAdd(&deg_r[(size_t)rep * n + row[i]], w[i]);
        pos[i] = atomicAdd(&counts_r[(size_t)rep * n + col[i]], 1);
    }
}

// ---------------- merge replicas: counts, xcdbase, dinv, bucket histogram ----------------

__global__ void repreduce_k(const int* __restrict__ counts_r, const float* __restrict__ deg_r,
                            int* __restrict__ counts, int* __restrict__ xcdbase,
                            float* __restrict__ dinv, int* bucketCount, int n) {
    __shared__ int h[NBUCKET];
    int tid = threadIdx.x;
    if (tid < NBUCKET) h[tid] = 0;
    __syncthreads();
    int node = blockIdx.x * blockDim.x + tid;
    int b = -1;
    if (node < n) {
        int total = 0;
#pragma unroll
        for (int r = 0; r < NREP; ++r) {
            xcdbase[(size_t)r * n + node] = total;
            total += counts_r[(size_t)r * n + node];
        }
        counts[node] = total;
        float deg = 1.0f;   // self-loop
#pragma unroll
        for (int r = 0; r < NREP; ++r) deg += deg_r[(size_t)r * n + node];
        dinv[node] = rsqrtf(fmaxf(deg, 1e-12f));
        b = min(NBUCKET - 1, total);
        atomicAdd(&h[b], 1);
    }
    __syncthreads();
    if (tid < NBUCKET && h[tid] > 0) atomicAdd(&bucketCount[tid], h[tid]);
}

// ---------------- bucket scan (tiny, 1 thread) ----------------

__global__ void bucketscan_k(const int* __restrict__ bucketCount, int* bucketBase,
                             int* bucketCur) {
    if (threadIdx.x == 0 && blockIdx.x == 0) {
        int run = 0;
        for (int b = 0; b < NBUCKET; ++b) {
            bucketBase[b] = run;
            bucketCur[b] = run;
            run += bucketCount[b];
        }
    }
}

// ---------------- place nodes into degree-sorted permutation ----------------

__global__ void placeperm_k(const int* __restrict__ counts, int* bucketCur,
                            int* __restrict__ perm, int n) {
    __shared__ int h[NBUCKET];
    __shared__ int base[NBUCKET];
    int tid = threadIdx.x;
    if (tid < NBUCKET) h[tid] = 0;
    __syncthreads();
    int node = blockIdx.x * blockDim.x + tid;
    int b = -1, rank = 0;
    if (node < n) {
        b = min(NBUCKET - 1, counts[node]);
        rank = atomicAdd(&h[b], 1);
    }
    __syncthreads();
    if (tid < NBUCKET && h[tid] > 0) base[tid] = atomicAdd(&bucketCur[tid], h[tid]);
    __syncthreads();
    if (node < n) perm[base[b] + rank] = node;
}

// ---------------- CSR offsets (scan over counts) ----------------

__global__ void scan1_k(const int* __restrict__ counts, int* offsets, int* blockSums, int n) {
    __shared__ int s[256];
    int tid = threadIdx.x;
    int idx = blockIdx.x * 256 + tid;
    int v = (idx < n) ? counts[idx] : 0;
    s[tid] = v;
    __syncthreads();
    for (int off = 1; off < 256; off <<= 1) {
        int t = (tid >= off) ? s[tid - off] : 0;
        __syncthreads();
        s[tid] += t;
        __syncthreads();
    }
    if (idx < n) offsets[idx] = s[tid] - v;
    if (tid == 255) blockSums[blockIdx.x] = s[255];
}

__global__ void scan2_k(int* blockSums, int nb) {
    __shared__ int s[1024];
    int tid = threadIdx.x;
    int v = (tid < nb) ? blockSums[tid] : 0;
    s[tid] = v;
    __syncthreads();
    for (int off = 1; off < 1024; off <<= 1) {
        int t = (tid >= off) ? s[tid - off] : 0;
        __syncthreads();
        s[tid] += t;
        __syncthreads();
    }
    if (tid < nb) blockSums[tid] = s[tid] - v;
}

__global__ void scan3_k(int* offsets, const int* __restrict__ blockSums, int n, int total) {
    int idx = blockIdx.x * blockDim.x + threadIdx.x;
    if (idx < n) offsets[idx] += blockSums[idx >> 8];
    if (idx == n) offsets[n] = total;
}

// ---------------- atomic-free scatter: csr = (src, RAW w) ----------------

__global__ void scatter_k(const int* __restrict__ row, const int* __restrict__ col,
                          const float* __restrict__ w,
                          const int* __restrict__ offsets, const int* __restrict__ xcdbase,
                          const int* __restrict__ pos, u64* __restrict__ csr, int e, int n) {
    int i = blockIdx.x * blockDim.x + threadIdx.x;
    int rep = blockIdx.x & (NREP - 1);
    if (i >= e) return;
    int c = col[i];
    int p = offsets[c] + xcdbase[(size_t)rep * n + c] + pos[i];
    u64 rec = (u64)(uint32)row[i] | ((u64)(uint32)__float_as_uint(w[i]) << 32);
    csr[p] = rec;
}

// ---------------- u-seed: ux = bf16(dinv * x), 2 floats / thread ----------------

__global__ void uxseed_k(const float* __restrict__ x, const float* __restrict__ dinv,
                         uint32* __restrict__ ux, int pairs) {
    int i = blockIdx.x * blockDim.x + threadIdx.x;
    if (i < pairs) {
        float di = dinv[i >> 5];          // 32 pairs per node
        float2 v = ((const float2*)x)[i];
        ux[i] = pk2(di * v.x, di * v.y);
    }
}

// ---------------- Horner in u-space: 4 degree-matched nodes per wave ----------------
// u = D^-1/2 z.  u_j = ux + dd * (W u_{j-1}),  (W u)[c] = u[c] + sum_e w_e u[src_e]
// MODE 0: u_out = bf16( ux + dd * (W u_in) )
// MODE 1: ybf   = bf16( 0.09*dinv*(W u_in) + 0.1*x )

template <int MODE>
__global__ __launch_bounds__(256) void horner4n_k(
    const unsigned short* __restrict__ u_in,
    unsigned short* __restrict__ u_out,
    unsigned short* __restrict__ ybf,
    const unsigned short* __restrict__ ux_bf,
    const float* __restrict__ x,
    const float* __restrict__ dinv,
    const int* __restrict__ offsets,
    const u64* __restrict__ csr,
    const int* __restrict__ perm,
    int n)
{
    int wv = __builtin_amdgcn_readfirstlane(threadIdx.x >> 6);
    int lane = threadIdx.x & 63;
    int g = lane >> 3;   // group
    int s = lane & 7;    // 16B slice of a 128B bf16 row
    int nbase = blockIdx.x * 16 + wv * 4;

    int nd[4], bb[4], ee[4];
#pragma unroll
    for (int m = 0; m < 4; ++m) {
        int idx = nbase + m;
        if (idx < n) {
            int node = perm[idx];
            nd[m] = node;
            bb[m] = offsets[node];
            ee[m] = offsets[node + 1];
        } else { nd[m] = 0; bb[m] = 0; ee[m] = 0; }
    }
    int maxd = max(max(ee[0] - bb[0], ee[1] - bb[1]), max(ee[2] - bb[2], ee[3] - bb[3]));

    float acc[4][8];
#pragma unroll
    for (int m = 0; m < 4; ++m)
#pragma unroll
        for (int i = 0; i < 8; ++i) acc[m][i] = 0.f;

    // prologue: load first csr batch
    u64 sw[4];
#pragma unroll
    for (int m = 0; m < 4; ++m) {
        int j = bb[m] + g;
        sw[m] = (j < ee[m]) ? csr[j] : 0ull;
    }

    for (int off = 0; off < maxd; off += 8) {
        uint4 q[4];
#pragma unroll
        for (int m = 0; m < 4; ++m)
            q[m] = ((const uint4*)(u_in + (size_t)(uint32)(sw[m] & 0xffffffffu) * 64))[s];
        u64 swn[4];
#pragma unroll
        for (int m = 0; m < 4; ++m) {
            int j = bb[m] + off + 8 + g;
            swn[m] = (j < ee[m]) ? csr[j] : 0ull;
        }
#pragma unroll
        for (int m = 0; m < 4; ++m) {
            float w = __uint_as_float((uint32)(sw[m] >> 32));
            acc[m][0] = fmaf(w, blo(q[m].x), acc[m][0]);
            acc[m][1] = fmaf(w, bhi(q[m].x), acc[m][1]);
            acc[m][2] = fmaf(w, blo(q[m].y), acc[m][2]);
            acc[m][3] = fmaf(w, bhi(q[m].y), acc[m][3]);
            acc[m][4] = fmaf(w, blo(q[m].z), acc[m][4]);
            acc[m][5] = fmaf(w, bhi(q[m].z), acc[m][5]);
            acc[m][6] = fmaf(w, blo(q[m].w), acc[m][6]);
            acc[m][7] = fmaf(w, bhi(q[m].w), acc[m][7]);
        }
#pragma unroll
        for (int m = 0; m < 4; ++m) sw[m] = swn[m];
    }

    // butterfly across the 8 groups (lane bits 3,4,5)
#pragma unroll
    for (int mask = 8; mask <= 32; mask <<= 1)
#pragma unroll
        for (int m = 0; m < 4; ++m)
#pragma unroll
            for (int i = 0; i < 8; ++i)
                acc[m][i] += __shfl_xor(acc[m][i], mask);

    // select node-g's sums with a static-index cndmask tree (no scratch)
    float t[8];
#pragma unroll
    for (int i = 0; i < 8; ++i) {
        float a01 = (g == 0) ? acc[0][i] : acc[1][i];
        float a23 = (g == 2) ? acc[2][i] : acc[3][i];
        t[i] = (g < 2) ? a01 : a23;
    }
    int n01 = (g == 0) ? nd[0] : nd[1];
    int n23 = (g == 2) ? nd[2] : nd[3];
    int nodeg = (g < 2) ? n01 : n23;

    if (g < 4 && nbase + g < n) {
        int node = nodeg;
        float di = dinv[node];
        uint4 zq = ((const uint4*)(u_in + (size_t)node * 64))[s];  // self u-row slice
        t[0] += blo(zq.x); t[1] += bhi(zq.x);
        t[2] += blo(zq.y); t[3] += bhi(zq.y);
        t[4] += blo(zq.z); t[5] += bhi(zq.z);
        t[6] += blo(zq.w); t[7] += bhi(zq.w);
        if (MODE == 0) {
            float dd = di * di;
            uint4 xq = ((const uint4*)(ux_bf + (size_t)node * 64))[s];
            uint4 o;
            o.x = pk2(fmaf(dd, t[0], blo(xq.x)), fmaf(dd, t[1], bhi(xq.x)));
            o.y = pk2(fmaf(dd, t[2], blo(xq.y)), fmaf(dd, t[3], bhi(xq.y)));
            o.z = pk2(fmaf(dd, t[4], blo(xq.z)), fmaf(dd, t[5], bhi(xq.z)));
            o.w = pk2(fmaf(dd, t[6], blo(xq.w)), fmaf(dd, t[7], bhi(xq.w)));
            ((uint4*)(u_out + (size_t)node * 64))[s] = o;
        } else {
            float c = 0.09f * di;
            const float4* xr = (const float4*)(x + (size_t)node * 64);
            float4 xa = xr[s * 2], xb = xr[s * 2 + 1];
            uint4 o;
            o.x = pk2(fmaf(c, t[0], 0.1f * xa.x), fmaf(c, t[1], 0.1f * xa.y));
            o.y = pk2(fmaf(c, t[2], 0.1f * xa.z), fmaf(c, t[3], 0.1f * xa.w));
            o.z = pk2(fmaf(c, t[4], 0.1f * xb.x), fmaf(c, t[5], 0.1f * xb.y));
            o.w = pk2(fmaf(c, t[6], 0.1f * xb.z), fmaf(c, t[7], 0.1f * xb.w));
            ((uint4*)(ybf + (size_t)node * 64))[s] = o;
        }
    }
}

// ---------------- MLP epilogue: y @ W0 relu @ W1 (y in bf16) ----------------

__global__ __launch_bounds__(256) void mlp_k(const unsigned short* __restrict__ ybf,
                                             const float* __restrict__ W0,
                                             const float* __restrict__ b0,
                                             const float* __restrict__ W1,
                                             const float* __restrict__ b1,
                                             float* __restrict__ out, int n) {
    __shared__ float W0s[64 * 64];
    __shared__ float W1s[64 * 32];
    __shared__ float b0s[64];
    __shared__ float b1s[32];
    __shared__ float z[32][64];
    __shared__ float hid[32][64];
    int tid = threadIdx.x;
    for (int i = tid; i < 64 * 64; i += 256) W0s[i] = W0[i];
    for (int i = tid; i < 64 * 32; i += 256) W1s[i] = W1[i];
    if (tid < 64) b0s[tid] = b0[tid];
    else if (tid < 96) b1s[tid - 64] = b1[tid - 64];

    int base = blockIdx.x * 32;
    const uint32* y32 = (const uint32*)ybf;
    for (int r = 0; r < 4; ++r) {
        int idx = r * 256 + tid;       // 1024 uints = 32 nodes x 32 uints
        int nn = idx >> 5, f2 = idx & 31;
        int node = base + nn;
        uint32 v = (node < n) ? y32[(size_t)node * 32 + f2] : 0u;
        z[nn][f2 * 2]     = blo(v);
        z[nn][f2 * 2 + 1] = bhi(v);
    }
    __syncthreads();
    for (int r = 0; r < 8; ++r) {
        int idx = r * 256 + tid;
        int nn = idx >> 6, j = idx & 63;
        float s = b0s[j];
#pragma unroll
        for (int i = 0; i < 64; ++i) s += z[nn][i] * W0s[i * 64 + j];
        hid[nn][j] = fmaxf(s, 0.f);
    }
    __syncthreads();
    for (int r = 0; r < 4; ++r) {
        int idx = r * 256 + tid;
        int nn = idx >> 5, o = idx & 31;
        int node = base + nn;
        if (node >= n) continue;
        float s = b1s[o];
#pragma unroll
        for (int i = 0; i < 64; ++i) s += hid[nn][i] * W1s[i * 32 + o];
        out[(size_t)node * 32 + o] = s;
    }
}

// ---------------- launch ----------------

extern "C" void kernel_launch(void* const* d_in, const int* in_sizes, int n_in,
                              void* d_out, int out_size, void* d_ws, size_t ws_size,
                              hipStream_t stream) {
    const float* x   = (const float*)d_in[0];
    const int*   ei  = (const int*)d_in[1];
    const float* ew  = (const float*)d_in[2];
    const float* W0  = (const float*)d_in[3];
    const float* b0  = (const float*)d_in[4];
    const float* W1  = (const float*)d_in[5];
    const float* b1  = (const float*)d_in[6];
    float* out = (float*)d_out;

    const int N = in_sizes[0] / 64;   // 100000
    const int E = in_sizes[2];        // 1200000
    const int* row = ei;
    const int* col = ei + E;

    char* p = (char*)d_ws;
    auto alloc = [&](size_t bytes) -> void* {
        void* r = (void*)p;
        p += (bytes + 255) & ~(size_t)255;
        return r;
    };
    int*   counts_r  = (int*)alloc((size_t)N * NREP * 4);
    float* deg_r     = (float*)alloc((size_t)N * NREP * 4);
    int*   xcdbase   = (int*)alloc((size_t)N * NREP * 4);
    int*   counts    = (int*)alloc((size_t)N * 4);
    float* dinv      = (float*)alloc((size_t)N * 4);
    int*   offsets   = (int*)alloc((size_t)(N + 1) * 4);
    int    nb        = (N + 255) / 256;
    int*   blockSums = (int*)alloc((size_t)nb * 4);
    int*   pos       = (int*)alloc((size_t)E * 4);
    u64*   csr       = (u64*)alloc((size_t)E * 8);
    int*   perm      = (int*)alloc((size_t)N * 4);
    int*   bucketCount = (int*)alloc(NBUCKET * 4);
    int*   bucketBase  = (int*)alloc(NBUCKET * 4);
    int*   bucketCur   = (int*)alloc(NBUCKET * 4);
    unsigned short* uxbf = (unsigned short*)alloc((size_t)N * 64 * 2);  // dinv*x bf16 == u0
    unsigned short* uA   = (unsigned short*)alloc((size_t)N * 64 * 2);
    unsigned short* uB   = (unsigned short*)alloc((size_t)N * 64 * 2);
    unsigned short* ybf  = (unsigned short*)alloc((size_t)N * 64 * 2);

    int gN  = (N + NTHREADS - 1) / NTHREADS;
    int gE  = (E + NTHREADS - 1) / NTHREADS;
    int gN8 = (N * NREP + NTHREADS - 1) / NTHREADS;

    repinit_k<<<gN8, NTHREADS, 0, stream>>>(counts_r, deg_r, bucketCount, N * NREP);
    edge_pass1_k<<<gE, NTHREADS, 0, stream>>>(row, col, ew, counts_r, deg_r, pos, E, N);
    repreduce_k<<<gN, NTHREADS, 0, stream>>>(counts_r, deg_r, counts, xcdbase, dinv,
                                             bucketCount, N);
    bucketscan_k<<<1, 64, 0, stream>>>(bucketCount, bucketBase, bucketCur);
    placeperm_k<<<gN, NTHREADS, 0, stream>>>(counts, bucketCur, perm, N);

    scan1_k<<<nb, 256, 0, stream>>>(counts, offsets, blockSums, N);
    scan2_k<<<1, 1024, 0, stream>>>(blockSums, nb);
    scan3_k<<<(N + 1 + NTHREADS - 1) / NTHREADS, NTHREADS, 0, stream>>>(offsets, blockSums, N, E);
    scatter_k<<<gE, NTHREADS, 0, stream>>>(row, col, ew, offsets, xcdbase, pos, csr, E, N);

    int pairs = N * 32;
    uxseed_k<<<(pairs + NTHREADS - 1) / NTHREADS, NTHREADS, 0, stream>>>(x, dinv,
                                                                         (uint32*)uxbf, pairs);

    // 9 Horner steps in u-space; first input is uxbf (= u0)
    int gP = (N + 15) / 16;
    const unsigned short* ui = uxbf;
    for (int k = 1; k <= 9; ++k) {
        unsigned short* uo = (ui == uA) ? uB : uA;
        horner4n_k<0><<<gP, 256, 0, stream>>>(ui, uo, nullptr, uxbf, x, dinv, offsets, csr,
                                              perm, N);
        ui = uo;
    }
    // final: ybf = bf16(0.09*dinv*(W u_9) + 0.1*x)
    horner4n_k<1><<<gP, 256, 0, stream>>>(ui, nullptr, ybf, uxbf, x, dinv, offsets, csr,
                                          perm, N);

    mlp_k<<<(N + 31) / 32, 256, 0, stream>>>(ybf, W0, b0, W1, b1, out, N);
}

// Round 9
// 508.198 us; speedup vs baseline: 1.1131x; 1.0891x over previous
//
#include <hip/hip_runtime.h>
#include <hip/hip_bf16.h>

#define NTHREADS 256
#define GB 1024            // edge-pass blocks (histogram / replay)
#define NB 256             // buckets (bucket = col >> 9; 196 used at N=100000)
#define BW 512             // cols per bucket

typedef unsigned int uint32;
typedef unsigned long long u64;

// ---------------- bf16 helpers ----------------

__device__ __forceinline__ float blo(uint32 u) { return __uint_as_float(u << 16); }
__device__ __forceinline__ float bhi(uint32 u) { return __uint_as_float(u & 0xffff0000u); }

__device__ __forceinline__ unsigned short bf16bits(float f) {
    __hip_bfloat16 h = __float2bfloat16(f);
    return *reinterpret_cast<unsigned short*>(&h);
}
__device__ __forceinline__ uint32 pk2(float a, float b) {
    return (uint32)bf16bits(a) | ((uint32)bf16bits(b) << 16);
}

// ---------------- init ----------------

__global__ void deginit_k(float* deg, int n) {
    int i = blockIdx.x * blockDim.x + threadIdx.x;
    if (i < n) deg[i] = 0.f;
}

// ---------------- K1: deg atomics (fire-and-forget) + col bucket histogram ----------------
// Block blk owns edges [blk*CH, min((blk+1)*CH, E)), threads strided 256.
// bh layout bucket-major: bh[bk*GB + blk].

__global__ __launch_bounds__(256) void histdeg_k(const int* __restrict__ row,
                                                 const int* __restrict__ col,
                                                 const float* __restrict__ w,
                                                 float* deg, int* __restrict__ bh,
                                                 int e, int ch) {
    __shared__ int hist[NB];
    int tid = threadIdx.x;
    hist[tid] = 0;
    __syncthreads();
    int beg = blockIdx.x * ch;
    int end = min(e, beg + ch);
    for (int i = beg + tid; i < end; i += 256) {
        unsafeAtomicAdd(&deg[row[i]], w[i]);
        atomicAdd(&hist[col[i] >> 9], 1);
    }
    __syncthreads();
    bh[(size_t)tid * GB + blockIdx.x] = hist[tid];
}

// ---------------- K2: per-bucket scan over the GB blocks ----------------

__global__ __launch_bounds__(256) void scanb_k(int* bh, int* tb) {
    __shared__ int s[256];
    int b = blockIdx.x;          // bucket
    int tid = threadIdx.x;
    size_t base = (size_t)b * GB + tid * 4;
    int v0 = bh[base], v1 = bh[base + 1], v2 = bh[base + 2], v3 = bh[base + 3];
    int tsum = v0 + v1 + v2 + v3;
    s[tid] = tsum;
    __syncthreads();
    for (int off = 1; off < 256; off <<= 1) {
        int t = (tid >= off) ? s[tid - off] : 0;
        __syncthreads();
        s[tid] += t;
        __syncthreads();
    }
    int excl = s[tid] - tsum;
    bh[base] = excl;
    bh[base + 1] = excl + v0;
    bh[base + 2] = excl + v0 + v1;
    bh[base + 3] = excl + v0 + v1 + v2;
    if (tid == 255) tb[b] = s[255];
}

// ---------------- K3: scan bucket totals -> global bucket bases ----------------

__global__ void scant_k(const int* __restrict__ tb, int* gb) {
    __shared__ int s[256];
    int tid = threadIdx.x;
    int v = tb[tid];
    s[tid] = v;
    __syncthreads();
    for (int off = 1; off < 256; off <<= 1) {
        int t = (tid >= off) ? s[tid - off] : 0;
        __syncthreads();
        s[tid] += t;
        __syncthreads();
    }
    gb[tid] = s[tid] - v;
    if (tid == 255) gb[256] = s[255];
}

// ---------------- K4: replay -> scatter edges into bucket-grouped staging ----------------

__global__ __launch_bounds__(256) void bscatter_k(const int* __restrict__ row,
                                                  const int* __restrict__ col,
                                                  const float* __restrict__ w,
                                                  const int* __restrict__ bh,
                                                  const int* __restrict__ gb,
                                                  int* __restrict__ st_col,
                                                  u64* __restrict__ st_rw,
                                                  int e, int ch) {
    __shared__ int hist[NB];
    int tid = threadIdx.x;
    hist[tid] = 0;
    __syncthreads();
    int beg = blockIdx.x * ch;
    int end = min(e, beg + ch);
    for (int i = beg + tid; i < end; i += 256) {
        int c = col[i];
        int bk = c >> 9;
        int rank = atomicAdd(&hist[bk], 1);                    // LDS, unique in (blk,bk)
        int slot = gb[bk] + bh[(size_t)bk * GB + blockIdx.x] + rank;
        st_col[slot] = c;
        st_rw[slot] = (u64)(uint32)row[i] | ((u64)__float_as_uint(w[i]) << 32);
    }
}

// ---------------- K5a: per-bucket node counts (LDS) ----------------

__global__ __launch_bounds__(256) void bcount_k(const int* __restrict__ st_col,
                                                const int* __restrict__ gb,
                                                int* __restrict__ counts, int n) {
    __shared__ int cnt[BW];
    int bk = blockIdx.x;
    int tid = threadIdx.x;
    cnt[tid] = 0; cnt[tid + 256] = 0;
    __syncthreads();
    int beg = gb[bk], end = gb[bk + 1];
    for (int j = beg + tid; j < end; j += 256)
        atomicAdd(&cnt[st_col[j] & (BW - 1)], 1);
    __syncthreads();
    int n0 = bk * BW + tid, n1 = n0 + 256;
    if (n0 < n) counts[n0] = cnt[tid];
    if (n1 < n) counts[n1] = cnt[tid + 256];
}

// ---------------- CSR offsets (scan over counts) ----------------

__global__ void scan1_k(const int* __restrict__ counts, int* offsets, int* blockSums, int n) {
    __shared__ int s[256];
    int tid = threadIdx.x;
    int idx = blockIdx.x * 256 + tid;
    int v = (idx < n) ? counts[idx] : 0;
    s[tid] = v;
    __syncthreads();
    for (int off = 1; off < 256; off <<= 1) {
        int t = (tid >= off) ? s[tid - off] : 0;
        __syncthreads();
        s[tid] += t;
        __syncthreads();
    }
    if (idx < n) offsets[idx] = s[tid] - v;
    if (tid == 255) blockSums[blockIdx.x] = s[255];
}

__global__ void scan2_k(int* blockSums, int nb) {
    __shared__ int s[1024];
    int tid = threadIdx.x;
    int v = (tid < nb) ? blockSums[tid] : 0;
    s[tid] = v;
    __syncthreads();
    for (int off = 1; off < 1024; off <<= 1) {
        int t = (tid >= off) ? s[tid - off] : 0;
        __syncthreads();
        s[tid] += t;
        __syncthreads();
    }
    if (tid < nb) blockSums[tid] = s[tid] - v;
}

__global__ void scan3_k(int* offsets, const int* __restrict__ blockSums, int n, int total) {
    int idx = blockIdx.x * blockDim.x + threadIdx.x;
    if (idx < n) offsets[idx] += blockSums[idx >> 8];
    if (idx == n) offsets[n] = total;
}

// ---------------- K5b: per-bucket final placement (LDS ranks) ----------------

__global__ __launch_bounds__(256) void bplace_k(const int* __restrict__ st_col,
                                                const u64* __restrict__ st_rw,
                                                const int* __restrict__ gb,
                                                const int* __restrict__ offsets,
                                                u64* __restrict__ csr) {
    __shared__ int cnt[BW];
    int bk = blockIdx.x;
    int tid = threadIdx.x;
    cnt[tid] = 0; cnt[tid + 256] = 0;
    __syncthreads();
    int beg = gb[bk], end = gb[bk + 1];
    for (int j = beg + tid; j < end; j += 256) {
        int c = st_col[j];
        int rank = atomicAdd(&cnt[c & (BW - 1)], 1);
        csr[offsets[c] + rank] = st_rw[j];
    }
}

// ---------------- dinv ----------------

__global__ void dinv_k(const float* __restrict__ deg, float* dinv, int n) {
    int i = blockIdx.x * blockDim.x + threadIdx.x;
    if (i < n) dinv[i] = rsqrtf(fmaxf(deg[i] + 1.0f, 1e-12f));   // +1 self-loop
}

// ---------------- u-seed: ux = bf16(dinv * x), 2 floats / thread ----------------

__global__ void uxseed_k(const float* __restrict__ x, const float* __restrict__ dinv,
                         uint32* __restrict__ ux, int pairs) {
    int i = blockIdx.x * blockDim.x + threadIdx.x;
    if (i < pairs) {
        float di = dinv[i >> 5];          // 32 pairs per node
        float2 v = ((const float2*)x)[i];
        ux[i] = pk2(di * v.x, di * v.y);
    }
}

// ---------------- Horner in u-space: 4 nodes per wave, csr-prefetch pipeline ----------------
// u = D^-1/2 z.  u_j = ux + dd * (W u_{j-1}),  (W u)[c] = u[c] + sum_e w_e u[src_e]
// MODE 0: u_out = bf16( ux + dd * (W u_in) )
// MODE 1: ybf   = bf16( 0.09*dinv*(W u_in) + 0.1*x )

template <int MODE>
__global__ __launch_bounds__(256) void horner4n_k(
    const unsigned short* __restrict__ u_in,
    unsigned short* __restrict__ u_out,
    unsigned short* __restrict__ ybf,
    const unsigned short* __restrict__ ux_bf,
    const float* __restrict__ x,
    const float* __restrict__ dinv,
    const int* __restrict__ offsets,
    const u64* __restrict__ csr,
    int n)
{
    int wv = __builtin_amdgcn_readfirstlane(threadIdx.x >> 6);
    int lane = threadIdx.x & 63;
    int g = lane >> 3;   // group
    int s = lane & 7;    // 16B slice of a 128B bf16 row
    int nbase = blockIdx.x * 16 + wv * 4;

    int bb[4], ee[4];
#pragma unroll
    for (int m = 0; m < 4; ++m) {
        int node = nbase + m;
        if (node < n) { bb[m] = offsets[node]; ee[m] = offsets[node + 1]; }
        else          { bb[m] = 0; ee[m] = 0; }
    }
    int maxd = max(max(ee[0] - bb[0], ee[1] - bb[1]), max(ee[2] - bb[2], ee[3] - bb[3]));

    float acc[4][8];
#pragma unroll
    for (int m = 0; m < 4; ++m)
#pragma unroll
        for (int i = 0; i < 8; ++i) acc[m][i] = 0.f;

    // prologue: load first csr batch
    u64 sw[4];
#pragma unroll
    for (int m = 0; m < 4; ++m) {
        int j = bb[m] + g;
        sw[m] = (j < ee[m]) ? csr[j] : 0ull;
    }

    for (int off = 0; off < maxd; off += 8) {
        uint4 q[4];
#pragma unroll
        for (int m = 0; m < 4; ++m)
            q[m] = ((const uint4*)(u_in + (size_t)(uint32)(sw[m] & 0xffffffffu) * 64))[s];
        u64 swn[4];
#pragma unroll
        for (int m = 0; m < 4; ++m) {
            int j = bb[m] + off + 8 + g;
            swn[m] = (j < ee[m]) ? csr[j] : 0ull;
        }
#pragma unroll
        for (int m = 0; m < 4; ++m) {
            float w = __uint_as_float((uint32)(sw[m] >> 32));
            acc[m][0] = fmaf(w, blo(q[m].x), acc[m][0]);
            acc[m][1] = fmaf(w, bhi(q[m].x), acc[m][1]);
            acc[m][2] = fmaf(w, blo(q[m].y), acc[m][2]);
            acc[m][3] = fmaf(w, bhi(q[m].y), acc[m][3]);
            acc[m][4] = fmaf(w, blo(q[m].z), acc[m][4]);
            acc[m][5] = fmaf(w, bhi(q[m].z), acc[m][5]);
            acc[m][6] = fmaf(w, blo(q[m].w), acc[m][6]);
            acc[m][7] = fmaf(w, bhi(q[m].w), acc[m][7]);
        }
#pragma unroll
        for (int m = 0; m < 4; ++m) sw[m] = swn[m];
    }

    // butterfly across the 8 groups (lane bits 3,4,5)
#pragma unroll
    for (int mask = 8; mask <= 32; mask <<= 1)
#pragma unroll
        for (int m = 0; m < 4; ++m)
#pragma unroll
            for (int i = 0; i < 8; ++i)
                acc[m][i] += __shfl_xor(acc[m][i], mask);

    // select node-g's sums with a static-index cndmask tree (no scratch)
    float t[8];
#pragma unroll
    for (int i = 0; i < 8; ++i) {
        float a01 = (g == 0) ? acc[0][i] : acc[1][i];
        float a23 = (g == 2) ? acc[2][i] : acc[3][i];
        t[i] = (g < 2) ? a01 : a23;
    }

    if (g < 4) {
        int node = nbase + g;
        if (node < n) {
            float di = dinv[node];
            uint4 zq = ((const uint4*)(u_in + (size_t)node * 64))[s];  // self u-row slice
            t[0] += blo(zq.x); t[1] += bhi(zq.x);
            t[2] += blo(zq.y); t[3] += bhi(zq.y);
            t[4] += blo(zq.z); t[5] += bhi(zq.z);
            t[6] += blo(zq.w); t[7] += bhi(zq.w);
            if (MODE == 0) {
                float dd = di * di;
                uint4 xq = ((const uint4*)(ux_bf + (size_t)node * 64))[s];
                uint4 o;
                o.x = pk2(fmaf(dd, t[0], blo(xq.x)), fmaf(dd, t[1], bhi(xq.x)));
                o.y = pk2(fmaf(dd, t[2], blo(xq.y)), fmaf(dd, t[3], bhi(xq.y)));
                o.z = pk2(fmaf(dd, t[4], blo(xq.z)), fmaf(dd, t[5], bhi(xq.z)));
                o.w = pk2(fmaf(dd, t[6], blo(xq.w)), fmaf(dd, t[7], bhi(xq.w)));
                ((uint4*)(u_out + (size_t)node * 64))[s] = o;
            } else {
                float c = 0.09f * di;
                const float4* xr = (const float4*)(x + (size_t)node * 64);
                float4 xa = xr[s * 2], xb = xr[s * 2 + 1];
                uint4 o;
                o.x = pk2(fmaf(c, t[0], 0.1f * xa.x), fmaf(c, t[1], 0.1f * xa.y));
                o.y = pk2(fmaf(c, t[2], 0.1f * xa.z), fmaf(c, t[3], 0.1f * xa.w));
                o.z = pk2(fmaf(c, t[4], 0.1f * xb.x), fmaf(c, t[5], 0.1f * xb.y));
                o.w = pk2(fmaf(c, t[6], 0.1f * xb.z), fmaf(c, t[7], 0.1f * xb.w));
                ((uint4*)(ybf + (size_t)node * 64))[s] = o;
            }
        }
    }
}

// ---------------- MLP epilogue: y @ W0 relu @ W1 (y in bf16) ----------------

__global__ __launch_bounds__(256) void mlp_k(const unsigned short* __restrict__ ybf,
                                             const float* __restrict__ W0,
                                             const float* __restrict__ b0,
                                             const float* __restrict__ W1,
                                             const float* __restrict__ b1,
                                             float* __restrict__ out, int n) {
    __shared__ float W0s[64 * 64];
    __shared__ float W1s[64 * 32];
    __shared__ float b0s[64];
    __shared__ float b1s[32];
    __shared__ float z[32][64];
    __shared__ float hid[32][64];
    int tid = threadIdx.x;
    for (int i = tid; i < 64 * 64; i += 256) W0s[i] = W0[i];
    for (int i = tid; i < 64 * 32; i += 256) W1s[i] = W1[i];
    if (tid < 64) b0s[tid] = b0[tid];
    else if (tid < 96) b1s[tid - 64] = b1[tid - 64];

    int base = blockIdx.x * 32;
    const uint32* y32 = (const uint32*)ybf;
    for (int r = 0; r < 4; ++r) {
        int idx = r * 256 + tid;       // 1024 uints = 32 nodes x 32 uints
        int nn = idx >> 5, f2 = idx & 31;
        int node = base + nn;
        uint32 v = (node < n) ? y32[(size_t)node * 32 + f2] : 0u;
        z[nn][f2 * 2]     = blo(v);
        z[nn][f2 * 2 + 1] = bhi(v);
    }
    __syncthreads();
    for (int r = 0; r < 8; ++r) {
        int idx = r * 256 + tid;
        int nn = idx >> 6, j = idx & 63;
        float s = b0s[j];
#pragma unroll
        for (int i = 0; i < 64; ++i) s += z[nn][i] * W0s[i * 64 + j];
        hid[nn][j] = fmaxf(s, 0.f);
    }
    __syncthreads();
    for (int r = 0; r < 4; ++r) {
        int idx = r * 256 + tid;
        int nn = idx >> 5, o = idx & 31;
        int node = base + nn;
        if (node >= n) continue;
        float s = b1s[o];
#pragma unroll
        for (int i = 0; i < 64; ++i) s += hid[nn][i] * W1s[i * 32 + o];
        out[(size_t)node * 32 + o] = s;
    }
}

// ---------------- launch ----------------

extern "C" void kernel_launch(void* const* d_in, const int* in_sizes, int n_in,
                              void* d_out, int out_size, void* d_ws, size_t ws_size,
                              hipStream_t stream) {
    const float* x   = (const float*)d_in[0];
    const int*   ei  = (const int*)d_in[1];
    const float* ew  = (const float*)d_in[2];
    const float* W0  = (const float*)d_in[3];
    const float* b0  = (const float*)d_in[4];
    const float* W1  = (const float*)d_in[5];
    const float* b1  = (const float*)d_in[6];
    float* out = (float*)d_out;

    const int N = in_sizes[0] / 64;   // 100000
    const int E = in_sizes[2];        // 1200000
    const int* row = ei;
    const int* col = ei + E;

    char* p = (char*)d_ws;
    auto alloc = [&](size_t bytes) -> void* {
        void* r = (void*)p;
        p += (bytes + 255) & ~(size_t)255;
        return r;
    };
    float* deg       = (float*)alloc((size_t)N * 4);
    float* dinv      = (float*)alloc((size_t)N * 4);
    int*   bh        = (int*)alloc((size_t)NB * GB * 4);    // 1 MB
    int*   tb        = (int*)alloc(NB * 4);
    int*   gb        = (int*)alloc((NB + 1) * 4);
    int*   st_col    = (int*)alloc((size_t)E * 4);
    u64*   st_rw     = (u64*)alloc((size_t)E * 8);
    int*   counts    = (int*)alloc((size_t)N * 4);
    int*   offsets   = (int*)alloc((size_t)(N + 1) * 4);
    int    nb        = (N + 255) / 256;
    int*   blockSums = (int*)alloc((size_t)nb * 4);
    u64*   csr       = (u64*)alloc((size_t)E * 8);
    unsigned short* uxbf = (unsigned short*)alloc((size_t)N * 64 * 2);  // dinv*x bf16 == u0
    unsigned short* uA   = (unsigned short*)alloc((size_t)N * 64 * 2);
    unsigned short* uB   = (unsigned short*)alloc((size_t)N * 64 * 2);
    unsigned short* ybf  = (unsigned short*)alloc((size_t)N * 64 * 2);

    int gN = (N + NTHREADS - 1) / NTHREADS;
    int ch = (E + GB - 1) / GB;       // edges per block in K1/K4

    deginit_k<<<gN, NTHREADS, 0, stream>>>(deg, N);
    histdeg_k<<<GB, 256, 0, stream>>>(row, col, ew, deg, bh, E, ch);
    scanb_k<<<NB, 256, 0, stream>>>(bh, tb);
    scant_k<<<1, 256, 0, stream>>>(tb, gb);
    bscatter_k<<<GB, 256, 0, stream>>>(row, col, ew, bh, gb, st_col, st_rw, E, ch);
    bcount_k<<<NB, 256, 0, stream>>>(st_col, gb, counts, N);

    scan1_k<<<nb, 256, 0, stream>>>(counts, offsets, blockSums, N);
    scan2_k<<<1, 1024, 0, stream>>>(blockSums, nb);
    scan3_k<<<(N + 1 + NTHREADS - 1) / NTHREADS, NTHREADS, 0, stream>>>(offsets, blockSums, N, E);
    bplace_k<<<NB, 256, 0, stream>>>(st_col, st_rw, gb, offsets, csr);

    dinv_k<<<gN, NTHREADS, 0, stream>>>(deg, dinv, N);
    int pairs = N * 32;
    uxseed_k<<<(pairs + NTHREADS - 1) / NTHREADS, NTHREADS, 0, stream>>>(x, dinv,
                                                                         (uint32*)uxbf, pairs);

    // 9 Horner steps in u-space; first input is uxbf (= u0)
    int gP = (N + 15) / 16;
    const unsigned short* ui = uxbf;
    for (int k = 1; k <= 9; ++k) {
        unsigned short* uo = (ui == uA) ? uB : uA;
        horner4n_k<0><<<gP, 256, 0, stream>>>(ui, uo, nullptr, uxbf, x, dinv, offsets, csr, N);
        ui = uo;
    }
    // final: ybf = bf16(0.09*dinv*(W u_9) + 0.1*x)
    horner4n_k<1><<<gP, 256, 0, stream>>>(ui, nullptr, ybf, uxbf, x, dinv, offsets, csr, N);

    mlp_k<<<(N + 31) / 32, 256, 0, stream>>>(ybf, W0, b0, W1, b1, out, N);
}

// Round 10
// 428.936 us; speedup vs baseline: 1.3188x; 1.1848x over previous
//
#include <hip/hip_runtime.h>
#include <hip/hip_bf16.h>

#define NTHREADS 256
#define GB 1024            // edge-pass blocks (histogram / replay)
#define NB 256             // buckets (bucket = id >> 9; 196 used at N=100000)
#define BW 512             // nodes per bucket

typedef unsigned int uint32;
typedef unsigned long long u64;
typedef __bf16 bf16x8 __attribute__((ext_vector_type(8)));
typedef float f32x4 __attribute__((ext_vector_type(4)));

// ---------------- bf16 helpers ----------------

__device__ __forceinline__ float blo(uint32 u) { return __uint_as_float(u << 16); }
__device__ __forceinline__ float bhi(uint32 u) { return __uint_as_float(u & 0xffff0000u); }

__device__ __forceinline__ unsigned short bf16bits(float f) {
    __hip_bfloat16 h = __float2bfloat16(f);
    return *reinterpret_cast<unsigned short*>(&h);
}
__device__ __forceinline__ uint32 pk2(float a, float b) {
    return (uint32)bf16bits(a) | ((uint32)bf16bits(b) << 16);
}

// ---------------- K1: dual bucket histogram (LDS only, no global atomics) ----------------

__global__ __launch_bounds__(256) void histcols_k(const int* __restrict__ row,
                                                  const int* __restrict__ col,
                                                  int* __restrict__ bh, int* __restrict__ bh2,
                                                  int e, int ch) {
    __shared__ int h1[NB], h2[NB];
    int tid = threadIdx.x;
    h1[tid] = 0; h2[tid] = 0;
    __syncthreads();
    int beg = blockIdx.x * ch;
    int end = min(e, beg + ch);
    for (int i = beg + tid; i < end; i += 256) {
        atomicAdd(&h1[col[i] >> 9], 1);
        atomicAdd(&h2[row[i] >> 9], 1);
    }
    __syncthreads();
    bh[(size_t)tid * GB + blockIdx.x] = h1[tid];
    bh2[(size_t)tid * GB + blockIdx.x] = h2[tid];
}

// ---------------- K2: per-bucket scan over the GB blocks (in-place excl prefix) ----------------

__global__ __launch_bounds__(256) void scanb_k(int* bh, int* tb) {
    __shared__ int s[256];
    int b = blockIdx.x;
    int tid = threadIdx.x;
    size_t base = (size_t)b * GB + tid * 4;
    int v0 = bh[base], v1 = bh[base + 1], v2 = bh[base + 2], v3 = bh[base + 3];
    int tsum = v0 + v1 + v2 + v3;
    s[tid] = tsum;
    __syncthreads();
    for (int off = 1; off < 256; off <<= 1) {
        int t = (tid >= off) ? s[tid - off] : 0;
        __syncthreads();
        s[tid] += t;
        __syncthreads();
    }
    int excl = s[tid] - tsum;
    bh[base] = excl;
    bh[base + 1] = excl + v0;
    bh[base + 2] = excl + v0 + v1;
    bh[base + 3] = excl + v0 + v1 + v2;
    if (tid == 255) tb[b] = s[255];
}

// ---------------- K3: scan bucket totals -> global bucket bases ----------------

__global__ void scant_k(const int* __restrict__ tb, int* gbase) {
    __shared__ int s[256];
    int tid = threadIdx.x;
    int v = tb[tid];
    s[tid] = v;
    __syncthreads();
    for (int off = 1; off < 256; off <<= 1) {
        int t = (tid >= off) ? s[tid - off] : 0;
        __syncthreads();
        s[tid] += t;
        __syncthreads();
    }
    gbase[tid] = s[tid] - v;
    if (tid == 255) gbase[256] = s[255];
}

// ---------------- K4: dual replay scatter into bucket-grouped staging ----------------

__global__ __launch_bounds__(256) void bscatter_k(const int* __restrict__ row,
                                                  const int* __restrict__ col,
                                                  const float* __restrict__ w,
                                                  const int* __restrict__ bh,
                                                  const int* __restrict__ bh2,
                                                  const int* __restrict__ gb,
                                                  const int* __restrict__ gb2,
                                                  int* __restrict__ st_col,
                                                  u64* __restrict__ st_rw,
                                                  u64* __restrict__ st2,
                                                  int e, int ch) {
    __shared__ int h1[NB], h2[NB];
    int tid = threadIdx.x;
    h1[tid] = 0; h2[tid] = 0;
    __syncthreads();
    int beg = blockIdx.x * ch;
    int end = min(e, beg + ch);
    for (int i = beg + tid; i < end; i += 256) {
        int c = col[i], r = row[i];
        float wv = w[i];
        u64 rec = (u64)(uint32)r | ((u64)__float_as_uint(wv) << 32);
        int bk = c >> 9;
        int rank = atomicAdd(&h1[bk], 1);
        int slot = gb[bk] + bh[(size_t)bk * GB + blockIdx.x] + rank;
        st_col[slot] = c;
        st_rw[slot] = rec;
        int bk2 = r >> 9;
        int rank2 = atomicAdd(&h2[bk2], 1);
        int slot2 = gb2[bk2] + bh2[(size_t)bk2 * GB + blockIdx.x] + rank2;
        st2[slot2] = rec;
    }
}

// ---------------- K5: per-bucket degree accumulation (LDS fp32) -> dinv ----------------

__global__ __launch_bounds__(256) void bdeg_k(const u64* __restrict__ st2,
                                              const int* __restrict__ gb2,
                                              float* __restrict__ dinv, int n) {
    __shared__ float facc[BW];
    int bk = blockIdx.x;
    int tid = threadIdx.x;
    facc[tid] = 0.f; facc[tid + 256] = 0.f;
    __syncthreads();
    int beg = gb2[bk], end = gb2[bk + 1];
    for (int j = beg + tid; j < end; j += 256) {
        u64 v = st2[j];
        int r = (int)(uint32)v;
        float wv = __uint_as_float((uint32)(v >> 32));
        atomicAdd(&facc[r & (BW - 1)], wv);
    }
    __syncthreads();
    int n0 = bk * BW + tid, n1 = n0 + 256;
    if (n0 < n) dinv[n0] = rsqrtf(fmaxf(facc[tid] + 1.f, 1e-12f));
    if (n1 < n) dinv[n1] = rsqrtf(fmaxf(facc[tid + 256] + 1.f, 1e-12f));
}

// ---------------- K6: per-bucket node counts (LDS) ----------------

__global__ __launch_bounds__(256) void bcount_k(const int* __restrict__ st_col,
                                                const int* __restrict__ gb,
                                                int* __restrict__ counts, int n) {
    __shared__ int cnt[BW];
    int bk = blockIdx.x;
    int tid = threadIdx.x;
    cnt[tid] = 0; cnt[tid + 256] = 0;
    __syncthreads();
    int beg = gb[bk], end = gb[bk + 1];
    for (int j = beg + tid; j < end; j += 256)
        atomicAdd(&cnt[st_col[j] & (BW - 1)], 1);
    __syncthreads();
    int n0 = bk * BW + tid, n1 = n0 + 256;
    if (n0 < n) counts[n0] = cnt[tid];
    if (n1 < n) counts[n1] = cnt[tid + 256];
}

// ---------------- CSR offsets (scan over counts) ----------------

__global__ void scan1_k(const int* __restrict__ counts, int* offsets, int* blockSums, int n) {
    __shared__ int s[256];
    int tid = threadIdx.x;
    int idx = blockIdx.x * 256 + tid;
    int v = (idx < n) ? counts[idx] : 0;
    s[tid] = v;
    __syncthreads();
    for (int off = 1; off < 256; off <<= 1) {
        int t = (tid >= off) ? s[tid - off] : 0;
        __syncthreads();
        s[tid] += t;
        __syncthreads();
    }
    if (idx < n) offsets[idx] = s[tid] - v;
    if (tid == 255) blockSums[blockIdx.x] = s[255];
}

__global__ void scan2_k(int* blockSums, int nb) {
    __shared__ int s[1024];
    int tid = threadIdx.x;
    int v = (tid < nb) ? blockSums[tid] : 0;
    s[tid] = v;
    __syncthreads();
    for (int off = 1; off < 1024; off <<= 1) {
        int t = (tid >= off) ? s[tid - off] : 0;
        __syncthreads();
        s[tid] += t;
        __syncthreads();
    }
    if (tid < nb) blockSums[tid] = s[tid] - v;
}

__global__ void scan3_k(int* offsets, const int* __restrict__ blockSums, int n, int total) {
    int idx = blockIdx.x * blockDim.x + threadIdx.x;
    if (idx < n) offsets[idx] += blockSums[idx >> 8];
    if (idx == n) offsets[n] = total;
}

// ---------------- K7: per-bucket final CSR placement ----------------

__global__ __launch_bounds__(256) void bplace_k(const int* __restrict__ st_col,
                                                const u64* __restrict__ st_rw,
                                                const int* __restrict__ gb,
                                                const int* __restrict__ offsets,
                                                u64* __restrict__ csr) {
    __shared__ int cnt[BW];
    int bk = blockIdx.x;
    int tid = threadIdx.x;
    cnt[tid] = 0; cnt[tid + 256] = 0;
    __syncthreads();
    int beg = gb[bk], end = gb[bk + 1];
    for (int j = beg + tid; j < end; j += 256) {
        int c = st_col[j];
        int rank = atomicAdd(&cnt[c & (BW - 1)], 1);
        csr[offsets[c] + rank] = st_rw[j];
    }
}

// ---------------- u-seed: ux = bf16(dinv * x) ----------------

__global__ void uxseed_k(const float* __restrict__ x, const float* __restrict__ dinv,
                         uint32* __restrict__ ux, int pairs) {
    int i = blockIdx.x * blockDim.x + threadIdx.x;
    if (i < pairs) {
        float di = dinv[i >> 5];          // 32 pairs per node
        float2 v = ((const float2*)x)[i];
        ux[i] = pk2(di * v.x, di * v.y);
    }
}

// ---------------- Horner in u-space: 4 nodes per wave, csr-prefetch pipeline ----------------

template <int MODE>
__global__ __launch_bounds__(256) void horner4n_k(
    const unsigned short* __restrict__ u_in,
    unsigned short* __restrict__ u_out,
    unsigned short* __restrict__ ybf,
    const unsigned short* __restrict__ ux_bf,
    const float* __restrict__ x,
    const float* __restrict__ dinv,
    const int* __restrict__ offsets,
    const u64* __restrict__ csr,
    int n)
{
    int wv = __builtin_amdgcn_readfirstlane(threadIdx.x >> 6);
    int lane = threadIdx.x & 63;
    int g = lane >> 3;   // group
    int s = lane & 7;    // 16B slice of a 128B bf16 row
    int nbase = blockIdx.x * 16 + wv * 4;

    int bb[4], ee[4];
#pragma unroll
    for (int m = 0; m < 4; ++m) {
        int node = nbase + m;
        if (node < n) { bb[m] = offsets[node]; ee[m] = offsets[node + 1]; }
        else          { bb[m] = 0; ee[m] = 0; }
    }
    int maxd = max(max(ee[0] - bb[0], ee[1] - bb[1]), max(ee[2] - bb[2], ee[3] - bb[3]));

    float acc[4][8];
#pragma unroll
    for (int m = 0; m < 4; ++m)
#pragma unroll
        for (int i = 0; i < 8; ++i) acc[m][i] = 0.f;

    u64 sw[4];
#pragma unroll
    for (int m = 0; m < 4; ++m) {
        int j = bb[m] + g;
        sw[m] = (j < ee[m]) ? csr[j] : 0ull;
    }

    for (int off = 0; off < maxd; off += 8) {
        uint4 q[4];
#pragma unroll
        for (int m = 0; m < 4; ++m)
            q[m] = ((const uint4*)(u_in + (size_t)(uint32)(sw[m] & 0xffffffffu) * 64))[s];
        u64 swn[4];
#pragma unroll
        for (int m = 0; m < 4; ++m) {
            int j = bb[m] + off + 8 + g;
            swn[m] = (j < ee[m]) ? csr[j] : 0ull;
        }
#pragma unroll
        for (int m = 0; m < 4; ++m) {
            float w = __uint_as_float((uint32)(sw[m] >> 32));
            acc[m][0] = fmaf(w, blo(q[m].x), acc[m][0]);
            acc[m][1] = fmaf(w, bhi(q[m].x), acc[m][1]);
            acc[m][2] = fmaf(w, blo(q[m].y), acc[m][2]);
            acc[m][3] = fmaf(w, bhi(q[m].y), acc[m][3]);
            acc[m][4] = fmaf(w, blo(q[m].z), acc[m][4]);
            acc[m][5] = fmaf(w, bhi(q[m].z), acc[m][5]);
            acc[m][6] = fmaf(w, blo(q[m].w), acc[m][6]);
            acc[m][7] = fmaf(w, bhi(q[m].w), acc[m][7]);
        }
#pragma unroll
        for (int m = 0; m < 4; ++m) sw[m] = swn[m];
    }

#pragma unroll
    for (int mask = 8; mask <= 32; mask <<= 1)
#pragma unroll
        for (int m = 0; m < 4; ++m)
#pragma unroll
            for (int i = 0; i < 8; ++i)
                acc[m][i] += __shfl_xor(acc[m][i], mask);

    float t[8];
#pragma unroll
    for (int i = 0; i < 8; ++i) {
        float a01 = (g == 0) ? acc[0][i] : acc[1][i];
        float a23 = (g == 2) ? acc[2][i] : acc[3][i];
        t[i] = (g < 2) ? a01 : a23;
    }

    if (g < 4) {
        int node = nbase + g;
        if (node < n) {
            float di = dinv[node];
            uint4 zq = ((const uint4*)(u_in + (size_t)node * 64))[s];  // self u-row slice
            t[0] += blo(zq.x); t[1] += bhi(zq.x);
            t[2] += blo(zq.y); t[3] += bhi(zq.y);
            t[4] += blo(zq.z); t[5] += bhi(zq.z);
            t[6] += blo(zq.w); t[7] += bhi(zq.w);
            if (MODE == 0) {
                float dd = di * di;
                uint4 xq = ((const uint4*)(ux_bf + (size_t)node * 64))[s];
                uint4 o;
                o.x = pk2(fmaf(dd, t[0], blo(xq.x)), fmaf(dd, t[1], bhi(xq.x)));
                o.y = pk2(fmaf(dd, t[2], blo(xq.y)), fmaf(dd, t[3], bhi(xq.y)));
                o.z = pk2(fmaf(dd, t[4], blo(xq.z)), fmaf(dd, t[5], bhi(xq.z)));
                o.w = pk2(fmaf(dd, t[6], blo(xq.w)), fmaf(dd, t[7], bhi(xq.w)));
                ((uint4*)(u_out + (size_t)node * 64))[s] = o;
            } else {
                float c = 0.09f * di;
                const float4* xr = (const float4*)(x + (size_t)node * 64);
                float4 xa = xr[s * 2], xb = xr[s * 2 + 1];
                uint4 o;
                o.x = pk2(fmaf(c, t[0], 0.1f * xa.x), fmaf(c, t[1], 0.1f * xa.y));
                o.y = pk2(fmaf(c, t[2], 0.1f * xa.z), fmaf(c, t[3], 0.1f * xa.w));
                o.z = pk2(fmaf(c, t[4], 0.1f * xb.x), fmaf(c, t[5], 0.1f * xb.y));
                o.w = pk2(fmaf(c, t[6], 0.1f * xb.z), fmaf(c, t[7], 0.1f * xb.w));
                ((uint4*)(ybf + (size_t)node * 64))[s] = o;
            }
        }
    }
}

// ---------------- MFMA MLP: relu(y@W0+b0)@W1+b1, bf16 inputs, fp32 accum ----------------
// Per block: 4 waves x 16 nodes. W0^T/W1^T staged bf16 in LDS, XOR-swizzled
// (chunk ^= row&7) so B-frag ds_read_b128 is ~conflict-free (G4 / T2 pattern).
// MFMA 16x16x32 layouts: A row=lane&15, k=(lane>>4)*8+e; B col=lane&15, same k;
// D col=lane&15, row=(lane>>4)*4+reg  [m89-verified].

__global__ __launch_bounds__(256) void mlp_mfma_k(const unsigned short* __restrict__ ybf,
                                                  const float* __restrict__ W0,
                                                  const float* __restrict__ b0,
                                                  const float* __restrict__ W1,
                                                  const float* __restrict__ b1,
                                                  float* __restrict__ out, int n) {
    __shared__ __align__(16) unsigned short W0t[64 * 64];   // [j][k^swz]
    __shared__ __align__(16) unsigned short W1t[32 * 64];
    __shared__ __align__(16) unsigned short hidL[4][16 * 64]; // per-wave [node][h^swz]
    __shared__ float b0s[64], b1s[32];
    int tid = threadIdx.x;
    for (int i = tid; i < 64 * 64; i += 256) {
        int k = i >> 6, j = i & 63;
        W0t[j * 64 + (k ^ ((j & 7) << 3))] = bf16bits(W0[i]);
    }
    for (int i = tid; i < 64 * 32; i += 256) {
        int k = i >> 5, j = i & 31;
        W1t[j * 64 + (k ^ ((j & 7) << 3))] = bf16bits(W1[i]);
    }
    if (tid < 64) b0s[tid] = b0[tid];
    else if (tid < 96) b1s[tid - 64] = b1[tid - 64];
    __syncthreads();

    int wave = tid >> 6, lane = tid & 63;
    int r = lane & 15, g = lane >> 4;
    int nbase = blockIdx.x * 64 + wave * 16;

    // layer 1 A-frags: y rows (clamped; invalid rows discarded at store)
    int nodeA = min(nbase + r, n - 1);
    const bf16x8* yrow = (const bf16x8*)(ybf + (size_t)nodeA * 64);
    bf16x8 A0 = yrow[g];
    bf16x8 A1 = yrow[4 + g];

#pragma unroll
    for (int t = 0; t < 4; ++t) {
        int j = t * 16 + r;
        int sj = j & 7;
        const bf16x8* wcol = (const bf16x8*)(W0t + j * 64);
        bf16x8 B0 = wcol[g ^ sj];
        bf16x8 B1 = wcol[(4 + g) ^ sj];
        float bv = b0s[j];
        f32x4 acc = {bv, bv, bv, bv};
        acc = __builtin_amdgcn_mfma_f32_16x16x32_bf16(A0, B0, acc, 0, 0, 0);
        acc = __builtin_amdgcn_mfma_f32_16x16x32_bf16(A1, B1, acc, 0, 0, 0);
#pragma unroll
        for (int v = 0; v < 4; ++v) {
            int i = g * 4 + v;     // node row within tile
            hidL[wave][i * 64 + (j ^ ((i & 7) << 3))] = bf16bits(fmaxf(acc[v], 0.f));
        }
    }
    // same-wave LDS write->read: compiler inserts lgkmcnt wait; no barrier needed

    const bf16x8* hrow = (const bf16x8*)(hidL[wave] + r * 64);
    int sr = r & 7;
    bf16x8 HA0 = hrow[g ^ sr];
    bf16x8 HA1 = hrow[(4 + g) ^ sr];
#pragma unroll
    for (int t = 0; t < 2; ++t) {
        int j = t * 16 + r;
        int sj = j & 7;
        const bf16x8* wcol = (const bf16x8*)(W1t + j * 64);
        bf16x8 B0 = wcol[g ^ sj];
        bf16x8 B1 = wcol[(4 + g) ^ sj];
        float bv = b1s[j];
        f32x4 acc = {bv, bv, bv, bv};
        acc = __builtin_amdgcn_mfma_f32_16x16x32_bf16(HA0, B0, acc, 0, 0, 0);
        acc = __builtin_amdgcn_mfma_f32_16x16x32_bf16(HA1, B1, acc, 0, 0, 0);
#pragma unroll
        for (int v = 0; v < 4; ++v) {
            int node = nbase + g * 4 + v;
            if (node < n) out[(size_t)node * 32 + j] = acc[v];
        }
    }
}

// ---------------- launch ----------------

extern "C" void kernel_launch(void* const* d_in, const int* in_sizes, int n_in,
                              void* d_out, int out_size, void* d_ws, size_t ws_size,
                              hipStream_t stream) {
    const float* x   = (const float*)d_in[0];
    const int*   ei  = (const int*)d_in[1];
    const float* ew  = (const float*)d_in[2];
    const float* W0  = (const float*)d_in[3];
    const float* b0  = (const float*)d_in[4];
    const float* W1  = (const float*)d_in[5];
    const float* b1  = (const float*)d_in[6];
    float* out = (float*)d_out;

    const int N = in_sizes[0] / 64;   // 100000
    const int E = in_sizes[2];        // 1200000
    const int* row = ei;
    const int* col = ei + E;

    char* p = (char*)d_ws;
    auto alloc = [&](size_t bytes) -> void* {
        void* r = (void*)p;
        p += (bytes + 255) & ~(size_t)255;
        return r;
    };
    float* dinv      = (float*)alloc((size_t)N * 4);
    int*   bh        = (int*)alloc((size_t)NB * GB * 4);
    int*   bh2       = (int*)alloc((size_t)NB * GB * 4);
    int*   tb        = (int*)alloc(NB * 4);
    int*   tb2       = (int*)alloc(NB * 4);
    int*   gb        = (int*)alloc((NB + 1) * 4);
    int*   gb2       = (int*)alloc((NB + 1) * 4);
    int*   st_col    = (int*)alloc((size_t)E * 4);
    u64*   st_rw     = (u64*)alloc((size_t)E * 8);
    int*   counts    = (int*)alloc((size_t)N * 4);
    int*   offsets   = (int*)alloc((size_t)(N + 1) * 4);
    int    nb        = (N + 255) / 256;
    int*   blockSums = (int*)alloc((size_t)nb * 4);
    u64*   csr       = (u64*)alloc((size_t)E * 8);   // doubles as st2 row-staging
    unsigned short* uxbf = (unsigned short*)alloc((size_t)N * 64 * 2);
    unsigned short* uA   = (unsigned short*)alloc((size_t)N * 64 * 2);
    unsigned short* uB   = (unsigned short*)alloc((size_t)N * 64 * 2);
    unsigned short* ybf  = (unsigned short*)alloc((size_t)N * 64 * 2);

    int ch = (E + GB - 1) / GB;

    histcols_k<<<GB, 256, 0, stream>>>(row, col, bh, bh2, E, ch);
    scanb_k<<<NB, 256, 0, stream>>>(bh, tb);
    scanb_k<<<NB, 256, 0, stream>>>(bh2, tb2);
    scant_k<<<1, 256, 0, stream>>>(tb, gb);
    scant_k<<<1, 256, 0, stream>>>(tb2, gb2);
    bscatter_k<<<GB, 256, 0, stream>>>(row, col, ew, bh, bh2, gb, gb2,
                                       st_col, st_rw, csr /*st2*/, E, ch);
    bdeg_k<<<NB, 256, 0, stream>>>(csr /*st2*/, gb2, dinv, N);
    bcount_k<<<NB, 256, 0, stream>>>(st_col, gb, counts, N);

    scan1_k<<<nb, 256, 0, stream>>>(counts, offsets, blockSums, N);
    scan2_k<<<1, 1024, 0, stream>>>(blockSums, nb);
    scan3_k<<<(N + 1 + NTHREADS - 1) / NTHREADS, NTHREADS, 0, stream>>>(offsets, blockSums, N, E);
    bplace_k<<<NB, 256, 0, stream>>>(st_col, st_rw, gb, offsets, csr);  // overwrites st2

    int pairs = N * 32;
    uxseed_k<<<(pairs + NTHREADS - 1) / NTHREADS, NTHREADS, 0, stream>>>(x, dinv,
                                                                         (uint32*)uxbf, pairs);

    // 9 Horner steps in u-space; first input is uxbf (= u0)
    int gP = (N + 15) / 16;
    const unsigned short* ui = uxbf;
    for (int k = 1; k <= 9; ++k) {
        unsigned short* uo = (ui == uA) ? uB : uA;
        horner4n_k<0><<<gP, 256, 0, stream>>>(ui, uo, nullptr, uxbf, x, dinv, offsets, csr, N);
        ui = uo;
    }
    // final: ybf = bf16(0.09*dinv*(W u_9) + 0.1*x)
    horner4n_k<1><<<gP, 256, 0, stream>>>(ui, nullptr, ybf, uxbf, x, dinv, offsets, csr, N);

    mlp_mfma_k<<<(N + 63) / 64, 256, 0, stream>>>(ybf, W0, b0, W1, b1, out, N);
}

// Round 11
// 413.771 us; speedup vs baseline: 1.3671x; 1.0367x over previous
//
#include <hip/hip_runtime.h>
#include <hip/hip_bf16.h>

#define NTHREADS 256
#define GB 256             // edge-pass blocks (histogram / replay)
#define NB 256             // buckets (bucket = id >> 9; 196 used at N=100000)
#define BW 512             // nodes per bucket

typedef unsigned int uint32;
typedef unsigned long long u64;
typedef __bf16 bf16x8 __attribute__((ext_vector_type(8)));
typedef float f32x4 __attribute__((ext_vector_type(4)));

// ---------------- bf16 helpers ----------------

__device__ __forceinline__ float blo(uint32 u) { return __uint_as_float(u << 16); }
__device__ __forceinline__ float bhi(uint32 u) { return __uint_as_float(u & 0xffff0000u); }

__device__ __forceinline__ unsigned short bf16bits(float f) {
    __hip_bfloat16 h = __float2bfloat16(f);
    return *reinterpret_cast<unsigned short*>(&h);
}
__device__ __forceinline__ uint32 pk2(float a, float b) {
    return (uint32)bf16bits(a) | ((uint32)bf16bits(b) << 16);
}

// ---------------- K1: dual bucket histogram (LDS only, no global atomics) ----------------

__global__ __launch_bounds__(256) void histcols_k(const int* __restrict__ row,
                                                  const int* __restrict__ col,
                                                  int* __restrict__ bh, int* __restrict__ bh2,
                                                  int e, int ch) {
    __shared__ int h1[NB], h2[NB];
    int tid = threadIdx.x;
    h1[tid] = 0; h2[tid] = 0;
    __syncthreads();
    int beg = blockIdx.x * ch;
    int end = min(e, beg + ch);
    for (int i = beg + tid; i < end; i += 256) {
        atomicAdd(&h1[col[i] >> 9], 1);
        atomicAdd(&h2[row[i] >> 9], 1);
    }
    __syncthreads();
    bh[(size_t)tid * GB + blockIdx.x] = h1[tid];
    bh2[(size_t)tid * GB + blockIdx.x] = h2[tid];
}

// ---------------- K2: per-bucket exclusive scan over the GB blocks ----------------

__global__ __launch_bounds__(256) void scanb_k(int* bh, int* tb) {
    __shared__ int s[GB];
    int b = blockIdx.x;
    int tid = threadIdx.x;          // one block-slot per thread (GB == 256)
    size_t base = (size_t)b * GB + tid;
    int v = bh[base];
    s[tid] = v;
    __syncthreads();
    for (int off = 1; off < GB; off <<= 1) {
        int t = (tid >= off) ? s[tid - off] : 0;
        __syncthreads();
        s[tid] += t;
        __syncthreads();
    }
    bh[base] = s[tid] - v;          // exclusive
    if (tid == GB - 1) tb[b] = s[GB - 1];
}

// ---------------- K3: scan bucket totals -> global bucket bases ----------------

__global__ void scant_k(const int* __restrict__ tb, int* gbase) {
    __shared__ int s[256];
    int tid = threadIdx.x;
    int v = tb[tid];
    s[tid] = v;
    __syncthreads();
    for (int off = 1; off < 256; off <<= 1) {
        int t = (tid >= off) ? s[tid - off] : 0;
        __syncthreads();
        s[tid] += t;
        __syncthreads();
    }
    gbase[tid] = s[tid] - v;
    if (tid == 255) gbase[256] = s[255];
}

// ---------------- K4: dual replay scatter into bucket-grouped staging ----------------
// st_col is u16: col & 511 (9 bits within bucket).

__global__ __launch_bounds__(256) void bscatter_k(const int* __restrict__ row,
                                                  const int* __restrict__ col,
                                                  const float* __restrict__ w,
                                                  const int* __restrict__ bh,
                                                  const int* __restrict__ bh2,
                                                  const int* __restrict__ gb,
                                                  const int* __restrict__ gb2,
                                                  unsigned short* __restrict__ st_col,
                                                  u64* __restrict__ st_rw,
                                                  u64* __restrict__ st2,
                                                  int e, int ch) {
    __shared__ int h1[NB], h2[NB];
    int tid = threadIdx.x;
    h1[tid] = 0; h2[tid] = 0;
    __syncthreads();
    int beg = blockIdx.x * ch;
    int end = min(e, beg + ch);
    for (int i = beg + tid; i < end; i += 256) {
        int c = col[i], r = row[i];
        float wv = w[i];
        u64 rec = (u64)(uint32)r | ((u64)__float_as_uint(wv) << 32);
        int bk = c >> 9;
        int rank = atomicAdd(&h1[bk], 1);
        int slot = gb[bk] + bh[(size_t)bk * GB + blockIdx.x] + rank;
        st_col[slot] = (unsigned short)(c & (BW - 1));
        st_rw[slot] = rec;
        int bk2 = r >> 9;
        int rank2 = atomicAdd(&h2[bk2], 1);
        int slot2 = gb2[bk2] + bh2[(size_t)bk2 * GB + blockIdx.x] + rank2;
        st2[slot2] = rec;
    }
}

// ---------------- K5: per-bucket degree accumulation (LDS fp32) -> dinv ----------------

__global__ __launch_bounds__(256) void bdeg_k(const u64* __restrict__ st2,
                                              const int* __restrict__ gb2,
                                              float* __restrict__ dinv, int n) {
    __shared__ float facc[BW];
    int bk = blockIdx.x;
    int tid = threadIdx.x;
    facc[tid] = 0.f; facc[tid + 256] = 0.f;
    __syncthreads();
    int beg = gb2[bk], end = gb2[bk + 1];
    for (int j = beg + tid; j < end; j += 256) {
        u64 v = st2[j];
        int r = (int)(uint32)v;
        float wv = __uint_as_float((uint32)(v >> 32));
        atomicAdd(&facc[r & (BW - 1)], wv);
    }
    __syncthreads();
    int n0 = bk * BW + tid, n1 = n0 + 256;
    if (n0 < n) dinv[n0] = rsqrtf(fmaxf(facc[tid] + 1.f, 1e-12f));
    if (n1 < n) dinv[n1] = rsqrtf(fmaxf(facc[tid + 256] + 1.f, 1e-12f));
}

// ---------------- K6: per-bucket node counts (LDS) ----------------

__global__ __launch_bounds__(256) void bcount_k(const unsigned short* __restrict__ st_col,
                                                const int* __restrict__ gb,
                                                int* __restrict__ counts, int n) {
    __shared__ int cnt[BW];
    int bk = blockIdx.x;
    int tid = threadIdx.x;
    cnt[tid] = 0; cnt[tid + 256] = 0;
    __syncthreads();
    int beg = gb[bk], end = gb[bk + 1];
    for (int j = beg + tid; j < end; j += 256)
        atomicAdd(&cnt[st_col[j]], 1);
    __syncthreads();
    int n0 = bk * BW + tid, n1 = n0 + 256;
    if (n0 < n) counts[n0] = cnt[tid];
    if (n1 < n) counts[n1] = cnt[tid + 256];
}

// ---------------- CSR offsets (scan over counts) ----------------

__global__ void scan1_k(const int* __restrict__ counts, int* offsets, int* blockSums, int n) {
    __shared__ int s[256];
    int tid = threadIdx.x;
    int idx = blockIdx.x * 256 + tid;
    int v = (idx < n) ? counts[idx] : 0;
    s[tid] = v;
    __syncthreads();
    for (int off = 1; off < 256; off <<= 1) {
        int t = (tid >= off) ? s[tid - off] : 0;
        __syncthreads();
        s[tid] += t;
        __syncthreads();
    }
    if (idx < n) offsets[idx] = s[tid] - v;
    if (tid == 255) blockSums[blockIdx.x] = s[255];
}

__global__ void scan2_k(int* blockSums, int nb) {
    __shared__ int s[1024];
    int tid = threadIdx.x;
    int v = (tid < nb) ? blockSums[tid] : 0;
    s[tid] = v;
    __syncthreads();
    for (int off = 1; off < 1024; off <<= 1) {
        int t = (tid >= off) ? s[tid - off] : 0;
        __syncthreads();
        s[tid] += t;
        __syncthreads();
    }
    if (tid < nb) blockSums[tid] = s[tid] - v;
}

__global__ void scan3_k(int* offsets, const int* __restrict__ blockSums, int n, int total) {
    int idx = blockIdx.x * blockDim.x + threadIdx.x;
    if (idx < n) offsets[idx] += blockSums[idx >> 8];
    if (idx == n) offsets[n] = total;
}

// ---------------- K7: per-bucket final CSR placement ----------------

__global__ __launch_bounds__(256) void bplace_k(const unsigned short* __restrict__ st_col,
                                                const u64* __restrict__ st_rw,
                                                const int* __restrict__ gb,
                                                const int* __restrict__ offsets,
                                                u64* __restrict__ csr) {
    __shared__ int cnt[BW];
    int bk = blockIdx.x;
    int tid = threadIdx.x;
    cnt[tid] = 0; cnt[tid + 256] = 0;
    __syncthreads();
    int beg = gb[bk], end = gb[bk + 1];
    for (int j = beg + tid; j < end; j += 256) {
        int c9 = st_col[j];
        int rank = atomicAdd(&cnt[c9], 1);
        int node = (bk << 9) | c9;
        csr[offsets[node] + rank] = st_rw[j];
    }
}

// ---------------- u-seed: ux = bf16(dinv * x) ----------------

__global__ void uxseed_k(const float* __restrict__ x, const float* __restrict__ dinv,
                         uint32* __restrict__ ux, int pairs) {
    int i = blockIdx.x * blockDim.x + threadIdx.x;
    if (i < pairs) {
        float di = dinv[i >> 5];          // 32 pairs per node
        float2 v = ((const float2*)x)[i];
        ux[i] = pk2(di * v.x, di * v.y);
    }
}

// ---------------- Horner in u-space: 4 nodes per wave, csr-prefetch pipeline ----------------

template <int MODE>
__global__ __launch_bounds__(256) void horner4n_k(
    const unsigned short* __restrict__ u_in,
    unsigned short* __restrict__ u_out,
    unsigned short* __restrict__ ybf,
    const unsigned short* __restrict__ ux_bf,
    const float* __restrict__ x,
    const float* __restrict__ dinv,
    const int* __restrict__ offsets,
    const u64* __restrict__ csr,
    int n)
{
    int wv = __builtin_amdgcn_readfirstlane(threadIdx.x >> 6);
    int lane = threadIdx.x & 63;
    int g = lane >> 3;   // group
    int s = lane & 7;    // 16B slice of a 128B bf16 row
    int nbase = blockIdx.x * 16 + wv * 4;

    int bb[4], ee[4];
#pragma unroll
    for (int m = 0; m < 4; ++m) {
        int node = nbase + m;
        if (node < n) { bb[m] = offsets[node]; ee[m] = offsets[node + 1]; }
        else          { bb[m] = 0; ee[m] = 0; }
    }
    int maxd = max(max(ee[0] - bb[0], ee[1] - bb[1]), max(ee[2] - bb[2], ee[3] - bb[3]));

    float acc[4][8];
#pragma unroll
    for (int m = 0; m < 4; ++m)
#pragma unroll
        for (int i = 0; i < 8; ++i) acc[m][i] = 0.f;

    u64 sw[4];
#pragma unroll
    for (int m = 0; m < 4; ++m) {
        int j = bb[m] + g;
        sw[m] = (j < ee[m]) ? csr[j] : 0ull;
    }

    for (int off = 0; off < maxd; off += 8) {
        uint4 q[4];
#pragma unroll
        for (int m = 0; m < 4; ++m)
            q[m] = ((const uint4*)(u_in + (size_t)(uint32)(sw[m] & 0xffffffffu) * 64))[s];
        u64 swn[4];
#pragma unroll
        for (int m = 0; m < 4; ++m) {
            int j = bb[m] + off + 8 + g;
            swn[m] = (j < ee[m]) ? csr[j] : 0ull;
        }
#pragma unroll
        for (int m = 0; m < 4; ++m) {
            float w = __uint_as_float((uint32)(sw[m] >> 32));
            acc[m][0] = fmaf(w, blo(q[m].x), acc[m][0]);
            acc[m][1] = fmaf(w, bhi(q[m].x), acc[m][1]);
            acc[m][2] = fmaf(w, blo(q[m].y), acc[m][2]);
            acc[m][3] = fmaf(w, bhi(q[m].y), acc[m][3]);
            acc[m][4] = fmaf(w, blo(q[m].z), acc[m][4]);
            acc[m][5] = fmaf(w, bhi(q[m].z), acc[m][5]);
            acc[m][6] = fmaf(w, blo(q[m].w), acc[m][6]);
            acc[m][7] = fmaf(w, bhi(q[m].w), acc[m][7]);
        }
#pragma unroll
        for (int m = 0; m < 4; ++m) sw[m] = swn[m];
    }

#pragma unroll
    for (int mask = 8; mask <= 32; mask <<= 1)
#pragma unroll
        for (int m = 0; m < 4; ++m)
#pragma unroll
            for (int i = 0; i < 8; ++i)
                acc[m][i] += __shfl_xor(acc[m][i], mask);

    float t[8];
#pragma unroll
    for (int i = 0; i < 8; ++i) {
        float a01 = (g == 0) ? acc[0][i] : acc[1][i];
        float a23 = (g == 2) ? acc[2][i] : acc[3][i];
        t[i] = (g < 2) ? a01 : a23;
    }

    if (g < 4) {
        int node = nbase + g;
        if (node < n) {
            float di = dinv[node];
            uint4 zq = ((const uint4*)(u_in + (size_t)node * 64))[s];  // self u-row slice
            t[0] += blo(zq.x); t[1] += bhi(zq.x);
            t[2] += blo(zq.y); t[3] += bhi(zq.y);
            t[4] += blo(zq.z); t[5] += bhi(zq.z);
            t[6] += blo(zq.w); t[7] += bhi(zq.w);
            if (MODE == 0) {
                float dd = di * di;
                uint4 xq = ((const uint4*)(ux_bf + (size_t)node * 64))[s];
                uint4 o;
                o.x = pk2(fmaf(dd, t[0], blo(xq.x)), fmaf(dd, t[1], bhi(xq.x)));
                o.y = pk2(fmaf(dd, t[2], blo(xq.y)), fmaf(dd, t[3], bhi(xq.y)));
                o.z = pk2(fmaf(dd, t[4], blo(xq.z)), fmaf(dd, t[5], bhi(xq.z)));
                o.w = pk2(fmaf(dd, t[6], blo(xq.w)), fmaf(dd, t[7], bhi(xq.w)));
                ((uint4*)(u_out + (size_t)node * 64))[s] = o;
            } else {
                float c = 0.09f * di;
                const float4* xr = (const float4*)(x + (size_t)node * 64);
                float4 xa = xr[s * 2], xb = xr[s * 2 + 1];
                uint4 o;
                o.x = pk2(fmaf(c, t[0], 0.1f * xa.x), fmaf(c, t[1], 0.1f * xa.y));
                o.y = pk2(fmaf(c, t[2], 0.1f * xa.z), fmaf(c, t[3], 0.1f * xa.w));
                o.z = pk2(fmaf(c, t[4], 0.1f * xb.x), fmaf(c, t[5], 0.1f * xb.y));
                o.w = pk2(fmaf(c, t[6], 0.1f * xb.z), fmaf(c, t[7], 0.1f * xb.w));
                ((uint4*)(ybf + (size_t)node * 64))[s] = o;
            }
        }
    }
}

// ---------------- MFMA MLP: relu(y@W0+b0)@W1+b1, bf16 inputs, fp32 accum ----------------

__global__ __launch_bounds__(256) void mlp_mfma_k(const unsigned short* __restrict__ ybf,
                                                  const float* __restrict__ W0,
                                                  const float* __restrict__ b0,
                                                  const float* __restrict__ W1,
                                                  const float* __restrict__ b1,
                                                  float* __restrict__ out, int n) {
    __shared__ __align__(16) unsigned short W0t[64 * 64];   // [j][k^swz]
    __shared__ __align__(16) unsigned short W1t[32 * 64];
    __shared__ __align__(16) unsigned short hidL[4][16 * 64]; // per-wave [node][h^swz]
    __shared__ float b0s[64], b1s[32];
    int tid = threadIdx.x;
    for (int i = tid; i < 64 * 64; i += 256) {
        int k = i >> 6, j = i & 63;
        W0t[j * 64 + (k ^ ((j & 7) << 3))] = bf16bits(W0[i]);
    }
    for (int i = tid; i < 64 * 32; i += 256) {
        int k = i >> 5, j = i & 31;
        W1t[j * 64 + (k ^ ((j & 7) << 3))] = bf16bits(W1[i]);
    }
    if (tid < 64) b0s[tid] = b0[tid];
    else if (tid < 96) b1s[tid - 64] = b1[tid - 64];
    __syncthreads();

    int wave = tid >> 6, lane = tid & 63;
    int r = lane & 15, g = lane >> 4;
    int nbase = blockIdx.x * 64 + wave * 16;

    int nodeA = min(nbase + r, n - 1);
    const bf16x8* yrow = (const bf16x8*)(ybf + (size_t)nodeA * 64);
    bf16x8 A0 = yrow[g];
    bf16x8 A1 = yrow[4 + g];

#pragma unroll
    for (int t = 0; t < 4; ++t) {
        int j = t * 16 + r;
        int sj = j & 7;
        const bf16x8* wcol = (const bf16x8*)(W0t + j * 64);
        bf16x8 B0 = wcol[g ^ sj];
        bf16x8 B1 = wcol[(4 + g) ^ sj];
        float bv = b0s[j];
        f32x4 acc = {bv, bv, bv, bv};
        acc = __builtin_amdgcn_mfma_f32_16x16x32_bf16(A0, B0, acc, 0, 0, 0);
        acc = __builtin_amdgcn_mfma_f32_16x16x32_bf16(A1, B1, acc, 0, 0, 0);
#pragma unroll
        for (int v = 0; v < 4; ++v) {
            int i = g * 4 + v;
            hidL[wave][i * 64 + (j ^ ((i & 7) << 3))] = bf16bits(fmaxf(acc[v], 0.f));
        }
    }

    const bf16x8* hrow = (const bf16x8*)(hidL[wave] + r * 64);
    int sr = r & 7;
    bf16x8 HA0 = hrow[g ^ sr];
    bf16x8 HA1 = hrow[(4 + g) ^ sr];
#pragma unroll
    for (int t = 0; t < 2; ++t) {
        int j = t * 16 + r;
        int sj = j & 7;
        const bf16x8* wcol = (const bf16x8*)(W1t + j * 64);
        bf16x8 B0 = wcol[g ^ sj];
        bf16x8 B1 = wcol[(4 + g) ^ sj];
        float bv = b1s[j];
        f32x4 acc = {bv, bv, bv, bv};
        acc = __builtin_amdgcn_mfma_f32_16x16x32_bf16(HA0, B0, acc, 0, 0, 0);
        acc = __builtin_amdgcn_mfma_f32_16x16x32_bf16(HA1, B1, acc, 0, 0, 0);
#pragma unroll
        for (int v = 0; v < 4; ++v) {
            int node = nbase + g * 4 + v;
            if (node < n) out[(size_t)node * 32 + j] = acc[v];
        }
    }
}

// ---------------- launch ----------------

extern "C" void kernel_launch(void* const* d_in, const int* in_sizes, int n_in,
                              void* d_out, int out_size, void* d_ws, size_t ws_size,
                              hipStream_t stream) {
    const float* x   = (const float*)d_in[0];
    const int*   ei  = (const int*)d_in[1];
    const float* ew  = (const float*)d_in[2];
    const float* W0  = (const float*)d_in[3];
    const float* b0  = (const float*)d_in[4];
    const float* W1  = (const float*)d_in[5];
    const float* b1  = (const float*)d_in[6];
    float* out = (float*)d_out;

    const int N = in_sizes[0] / 64;   // 100000
    const int E = in_sizes[2];        // 1200000
    const int* row = ei;
    const int* col = ei + E;

    char* p = (char*)d_ws;
    auto alloc = [&](size_t bytes) -> void* {
        void* r = (void*)p;
        p += (bytes + 255) & ~(size_t)255;
        return r;
    };
    float* dinv      = (float*)alloc((size_t)N * 4);
    int*   bh        = (int*)alloc((size_t)NB * GB * 4);
    int*   bh2       = (int*)alloc((size_t)NB * GB * 4);
    int*   tb        = (int*)alloc(NB * 4);
    int*   tb2       = (int*)alloc(NB * 4);
    int*   gb        = (int*)alloc((NB + 1) * 4);
    int*   gb2       = (int*)alloc((NB + 1) * 4);
    unsigned short* st_col = (unsigned short*)alloc((size_t)E * 2);
    u64*   st_rw     = (u64*)alloc((size_t)E * 8);
    int*   counts    = (int*)alloc((size_t)N * 4);
    int*   offsets   = (int*)alloc((size_t)(N + 1) * 4);
    int    nb        = (N + 255) / 256;
    int*   blockSums = (int*)alloc((size_t)nb * 4);
    u64*   csr       = (u64*)alloc((size_t)E * 8);   // doubles as st2 row-staging
    unsigned short* uxbf = (unsigned short*)alloc((size_t)N * 64 * 2);
    unsigned short* uA   = (unsigned short*)alloc((size_t)N * 64 * 2);
    unsigned short* uB   = (unsigned short*)alloc((size_t)N * 64 * 2);
    unsigned short* ybf  = (unsigned short*)alloc((size_t)N * 64 * 2);

    int ch = (E + GB - 1) / GB;

    histcols_k<<<GB, 256, 0, stream>>>(row, col, bh, bh2, E, ch);
    scanb_k<<<NB, 256, 0, stream>>>(bh, tb);
    scanb_k<<<NB, 256, 0, stream>>>(bh2, tb2);
    scant_k<<<1, 256, 0, stream>>>(tb, gb);
    scant_k<<<1, 256, 0, stream>>>(tb2, gb2);
    bscatter_k<<<GB, 256, 0, stream>>>(row, col, ew, bh, bh2, gb, gb2,
                                       st_col, st_rw, csr /*st2*/, E, ch);
    bdeg_k<<<NB, 256, 0, stream>>>(csr /*st2*/, gb2, dinv, N);
    bcount_k<<<NB, 256, 0, stream>>>(st_col, gb, counts, N);

    scan1_k<<<nb, 256, 0, stream>>>(counts, offsets, blockSums, N);
    scan2_k<<<1, 1024, 0, stream>>>(blockSums, nb);
    scan3_k<<<(N + 1 + NTHREADS - 1) / NTHREADS, NTHREADS, 0, stream>>>(offsets, blockSums, N, E);
    bplace_k<<<NB, 256, 0, stream>>>(st_col, st_rw, gb, offsets, csr);  // overwrites st2

    int pairs = N * 32;
    uxseed_k<<<(pairs + NTHREADS - 1) / NTHREADS, NTHREADS, 0, stream>>>(x, dinv,
                                                                         (uint32*)uxbf, pairs);

    // 9 Horner steps in u-space; first input is uxbf (= u0)
    int gP = (N + 15) / 16;
    const unsigned short* ui = uxbf;
    for (int k = 1; k <= 9; ++k) {
        unsigned short* uo = (ui == uA) ? uB : uA;
        horner4n_k<0><<<gP, 256, 0, stream>>>(ui, uo, nullptr, uxbf, x, dinv, offsets, csr, N);
        ui = uo;
    }
    // final: ybf = bf16(0.09*dinv*(W u_9) + 0.1*x)
    horner4n_k<1><<<gP, 256, 0, stream>>>(ui, nullptr, ybf, uxbf, x, dinv, offsets, csr, N);

    mlp_mfma_k<<<(N + 63) / 64, 256, 0, stream>>>(ybf, W0, b0, W1, b1, out, N);
}